// Round 1
// baseline (1500.453 us; speedup 1.0000x reference)
//
#include <hip/hip_runtime.h>

#define D 200
#define BNS_F 0.9999950000374997f   // 1/sqrt(1+1e-5)

typedef float f32x4 __attribute__((ext_vector_type(4)));
typedef short s16x8 __attribute__((ext_vector_type(8)));

static __device__ __forceinline__ unsigned short f2b(float f) {
  union { float f; unsigned u; } v; v.f = f;
  return (unsigned short)((v.u + 0x7FFFu + ((v.u >> 16) & 1u)) >> 16);
}
static __device__ __forceinline__ float b2f(unsigned short h) {
  union { unsigned u; float f; } v; v.u = ((unsigned)h) << 16;
  return v.f;
}

// ---------------- prep kernels ----------------

__global__ __launch_bounds__(256) void k_cvt_bf16(const float* __restrict__ src,
                                                  unsigned short* __restrict__ dst, int n) {
  int stride = gridDim.x * 256;
  for (int i = blockIdx.x * 256 + threadIdx.x; i < n; i += stride) dst[i] = f2b(src[i]);
}

// W1p[k][i][j] = 0.5 * pos[k][i] * w_alle[k*200+i][j], packed in MFMA B-fragment order.
// blk = (ks*7 + kt)*13 + nt ; elem (lane, t): kk = kt*32 + (lane>>4)*8 + t, j = nt*16 + (lane&15)
__global__ __launch_bounds__(64) void k_prep_w1p(const float* __restrict__ E,
                                                 const float* __restrict__ w_alle,
                                                 const int* __restrict__ entp,
                                                 unsigned short* __restrict__ Wpk) {
  int blk = blockIdx.x;
  int lane = threadIdx.x;
  int nt = blk % 13; int rem = blk / 13; int kt = rem % 7; int ks = rem / 7;
  int ent = *entp;
  int j = nt * 16 + (lane & 15);
  unsigned short* p = Wpk + (size_t)blk * 512 + lane * 8;
#pragma unroll
  for (int t = 0; t < 8; ++t) {
    int kk = kt * 32 + ((lane >> 4) << 3) + t;
    float v = 0.f;
    if (kk < D && j < D)
      v = 0.5f * E[(size_t)(ent + ks) * D + kk] * w_alle[(size_t)(ks * D + kk) * D + j];
    p[t] = f2b(v);
  }
}

// Wcc (400 x 200) fp32: rows 0..199 = w_alleandr @ w_addpos[0:200], rows 200..399 = w_addpos[200:400]
__global__ __launch_bounds__(256) void k_prep_wcc(const float* __restrict__ w_alleandr,
                                                  const float* __restrict__ w_addpos,
                                                  float* __restrict__ Wcc) {
  int t = blockIdx.x;
  int j = threadIdx.x;
  if (j >= D) return;
  float v;
  if (t < D) {
    float acc = 0.f;
    for (int u = 0; u < D; ++u) acc += w_alleandr[t * D + u] * w_addpos[u * D + j];
    v = acc;
  } else {
    v = w_addpos[t * D + j];
  }
  Wcc[t * D + j] = v;
}

// fc_w (K x 200) -> packed bf16 fragments [kt][nt][512], K padded, N padded to 208
__global__ __launch_bounds__(64) void k_prep_wfc(const float* __restrict__ fc_w,
                                                 unsigned short* __restrict__ Wpk, int K) {
  int blk = blockIdx.x;   // kt*13 + nt
  int lane = threadIdx.x;
  int nt = blk % 13; int kt = blk / 13;
  int j = nt * 16 + (lane & 15);
  unsigned short* p = Wpk + (size_t)blk * 512 + lane * 8;
#pragma unroll
  for (int t = 0; t < 8; ++t) {
    int kk = kt * 32 + ((lane >> 4) << 3) + t;
    float v = (kk < K && j < D) ? fc_w[(size_t)kk * D + j] : 0.f;
    p[t] = f2b(v);
  }
}

// ---------------- needed-node mask + compaction ----------------

__global__ __launch_bounds__(256) void k_mask(const int* __restrict__ e1, const int* __restrict__ e2,
                                              const int* __restrict__ e3, const int* __restrict__ e4,
                                              const int* __restrict__ e5, const int* __restrict__ e6,
                                              const int* __restrict__ entp,
                                              int* __restrict__ needed, int B) {
  int t = blockIdx.x * 256 + threadIdx.x;
  int total = 6 * B;
  if (t < total) {
    int k = t / B, b = t - k * B;
    const int* p = (k == 0) ? e1 : (k == 1) ? e2 : (k == 2) ? e3 : (k == 3) ? e4 : (k == 4) ? e5 : e6;
    needed[p[b]] = 1;
  } else if (t < total + 6) {
    needed[*entp + (t - total)] = 1;
  }
}

__global__ __launch_bounds__(256) void k_compact(const int* __restrict__ needed,
                                                 int* __restrict__ list, int* __restrict__ cnt, int Nn) {
  int n = blockIdx.x * 256 + threadIdx.x;
  if (n < Nn && needed[n]) {
    int p = atomicAdd(cnt, 1);
    list[p] = n;
  }
}

// ---------------- U GEMM (MFMA): U[h] = sum_k Ebf[he[h,1+k]] @ W1p[k] + 0.5*R[he[h,0]] ----------------
// M-tile 64 hyperedges per block, N = 13 nt tiles split across 4 waves, K = 6 slots x 7 kt (pad 224)

#define U_LDA 116   // u32 per LDS A row (= 232 bf16; 200 data + pad)

__global__ __launch_bounds__(256) void k_ugemm(const unsigned int* __restrict__ Ebf32,
                                               const float* __restrict__ Rm,
                                               const int* __restrict__ he,
                                               const unsigned short* __restrict__ Wpk,
                                               unsigned short* __restrict__ Ubf, int H) {
  __shared__ unsigned int Alds[64 * U_LDA];
  __shared__ int helds[64][7];
  int tid = threadIdx.x;
  int lane = tid & 63, wid = tid >> 6;
  int h0 = blockIdx.x * 64;

  for (int u = tid; u < 64 * 7; u += 256) {
    int r = u / 7, c = u - r * 7;
    int hg = h0 + r; if (hg >= H) hg = H - 1;
    helds[r][c] = he[(size_t)hg * 7 + c];
  }

  int nt0 = (wid == 0) ? 0 : (wid == 1) ? 4 : (wid == 2) ? 7 : 10;
  int ntc = (wid == 0) ? 4 : 3;

  f32x4 acc[4][4];
#pragma unroll
  for (int a = 0; a < 4; ++a)
#pragma unroll
    for (int b = 0; b < 4; ++b) acc[a][b] = (f32x4){0.f, 0.f, 0.f, 0.f};

  for (int ks = 0; ks < 6; ++ks) {
    __syncthreads();
    for (int u = tid; u < 64 * U_LDA; u += 256) {
      int r = u / U_LDA, c = u - r * U_LDA;
      unsigned int val = 0;
      if (c < 100) {
        int eidx = helds[r][1 + ks];
        val = Ebf32[(size_t)eidx * 100 + c];
      }
      Alds[u] = val;
    }
    __syncthreads();
#pragma unroll
    for (int kt = 0; kt < 7; ++kt) {
      s16x8 afr[4];
#pragma unroll
      for (int rt = 0; rt < 4; ++rt) {
        int row = rt * 16 + (lane & 15);
        afr[rt] = *(const s16x8*)((const unsigned short*)Alds + row * (U_LDA * 2) + kt * 32 + ((lane >> 4) << 3));
      }
#pragma unroll
      for (int ln = 0; ln < 4; ++ln) {
        if (ln < ntc) {
          int nt = nt0 + ln;
          s16x8 bfr = *(const s16x8*)(Wpk + ((size_t)((ks * 7 + kt) * 13 + nt)) * 512 + lane * 8);
#pragma unroll
          for (int rt = 0; rt < 4; ++rt)
            acc[rt][ln] = __builtin_amdgcn_mfma_f32_16x16x32_bf16(afr[rt], bfr, acc[rt][ln], 0, 0, 0);
        }
      }
    }
  }
  // epilogue: C layout row=(lane>>4)*4+r, col=lane&15
#pragma unroll
  for (int rt = 0; rt < 4; ++rt) {
#pragma unroll
    for (int ln = 0; ln < 4; ++ln) {
      if (ln < ntc) {
        int j = (nt0 + ln) * 16 + (lane & 15);
        if (j < D) {
#pragma unroll
          for (int r = 0; r < 4; ++r) {
            int row = rt * 16 + ((lane >> 4) << 2) + r;
            int h = h0 + row;
            if (h < H) {
              float v = acc[rt][ln][r] + 0.5f * Rm[(size_t)helds[row][0] * D + j];
              Ubf[(size_t)h * D + j] = f2b(v);
            }
          }
        }
      }
    }
  }
}

// ---------------- edge scatter: S[src][0:200] += U[et], S[src][200:400] += E[dst] ----------------

__global__ __launch_bounds__(256) void k_scatter(const int* __restrict__ esrc, const int* __restrict__ edst,
                                                 const int* __restrict__ etyp, const int* __restrict__ needed,
                                                 const unsigned short* __restrict__ Ubf,
                                                 const float* __restrict__ E,
                                                 float* __restrict__ S, int NEdge) {
  int wave = blockIdx.x * 4 + (threadIdx.x >> 6);
  int lane = threadIdx.x & 63;
  if (wave >= NEdge) return;
  int s = esrc[wave];
  if (!needed[s]) return;
  int et = etyp[wave];
  int dd = edst[wave];
  float* Sr = S + (size_t)s * 400;
  for (int c = lane; c < 400; c += 64) {
    float v = (c < D) ? b2f(Ubf[(size_t)et * D + c]) : E[(size_t)dd * D + (c - D)];
    atomicAdd(Sr + c, v);
  }
}

// ---------------- agg -> outE for needed nodes (8 per block) ----------------

__global__ __launch_bounds__(256) void k_aggout(const int* __restrict__ list, const int* __restrict__ cnt,
                                                const float* __restrict__ S, const float* __restrict__ Wcc,
                                                const float* __restrict__ E,
                                                const float* __restrict__ bnmp_g, const float* __restrict__ bnmp_b,
                                                float* __restrict__ outE) {
  __shared__ float Slds[8][400];
  __shared__ int nodes[8];
  int tid = threadIdx.x;
  int base = blockIdx.x * 8;
  int count = *cnt;
  if (base >= count) return;
  if (tid < 8) nodes[tid] = (base + tid < count) ? list[base + tid] : -1;
  __syncthreads();
  for (int u = tid; u < 8 * 400; u += 256) {
    int m = u / 400, t = u - m * 400;
    int n = nodes[m];
    Slds[m][t] = (n >= 0) ? S[(size_t)n * 400 + t] : 0.f;
  }
  __syncthreads();
  int j = tid;
  if (j >= D) return;
  float acc[8] = {0.f, 0.f, 0.f, 0.f, 0.f, 0.f, 0.f, 0.f};
  for (int t = 0; t < 400; ++t) {
    float w = Wcc[t * D + j];
#pragma unroll
    for (int m = 0; m < 8; ++m) acc[m] += Slds[m][t] * w;
  }
  float gs = bnmp_g[j] * BNS_F;
  float gb = bnmp_b[j];
#pragma unroll
  for (int m = 0; m < 8; ++m) {
    int n = nodes[m];
    if (n >= 0) {
      float v = 0.5f * acc[m] + 0.5f * E[(size_t)n * D + j];
      outE[(size_t)n * D + j] = tanhf(v * gs + gb);
    }
  }
}

// ---------------- outR = R @ w_rel ----------------

__global__ __launch_bounds__(256) void k_outr(const float* __restrict__ Rm, const float* __restrict__ w_rel,
                                              float* __restrict__ outR) {
  int r = blockIdx.x; int j = threadIdx.x;
  if (j >= D) return;
  float acc = 0.f;
  for (int t = 0; t < D; ++t) acc += Rm[(size_t)r * D + t] * w_rel[t * D + j];
  outR[(size_t)r * D + j] = acc;
}

// ---------------- build stk (B x 7 x 200), bn0 folded in ----------------

__global__ __launch_bounds__(256) void k_stk(const float* __restrict__ outE, const float* __restrict__ outR,
                                             const int* __restrict__ r_idx,
                                             const int* __restrict__ e1, const int* __restrict__ e2,
                                             const int* __restrict__ e3, const int* __restrict__ e4,
                                             const int* __restrict__ e5, const int* __restrict__ e6,
                                             const float* __restrict__ ms, const int* __restrict__ entp,
                                             const float* __restrict__ bn0_g, const float* __restrict__ bn0_b,
                                             float* __restrict__ stk) {
  int b = blockIdx.x; int j = threadIdx.x;
  if (j >= D) return;
  int ent = *entp;
  float s0 = bn0_g[0] * BNS_F, b0 = bn0_b[0];
  float* out = stk + (size_t)b * 1400;
  out[j] = outR[(size_t)r_idx[b] * D + j] * s0 + b0;
#pragma unroll
  for (int k = 0; k < 6; ++k) {
    const int* ep = (k == 0) ? e1 : (k == 1) ? e2 : (k == 2) ? e3 : (k == 3) ? e4 : (k == 4) ? e5 : e6;
    float q = outE[(size_t)(ent + k) * D + j];
    float v = outE[(size_t)ep[b] * D + j] * q * ms[(size_t)b * 6 + k];
    out[(1 + k) * D + j] = v * s0 + b0;
  }
}

// ---------------- conv (7x3 VALID) + conv_b + bn1 + relu -> x1 bf16 (B x 39600) ----------------

__global__ __launch_bounds__(256) void k_conv(const float* __restrict__ stk, const float* __restrict__ conv_w,
                                              const float* __restrict__ conv_b, const float* __restrict__ bn1_g,
                                              const float* __restrict__ bn1_b, unsigned short* __restrict__ x1) {
  __shared__ float srow[1400];
  __shared__ float cw[4200];
  __shared__ float cb[200], g1[200], b1[200];
  int b = blockIdx.x, tid = threadIdx.x;
  for (int u = tid; u < 1400; u += 256) srow[u] = stk[(size_t)b * 1400 + u];
  for (int u = tid; u < 4200; u += 256) cw[u] = conv_w[u];
  if (tid < 200) { cb[tid] = conv_b[tid]; g1[tid] = bn1_g[tid] * BNS_F; b1[tid] = bn1_b[tid]; }
  __syncthreads();
  for (int idx = tid; idx < 200 * 198; idx += 256) {
    int f = idx / 198, w = idx - f * 198;
    float acc = 0.f;
#pragma unroll
    for (int kh = 0; kh < 7; ++kh)
#pragma unroll
      for (int kw = 0; kw < 3; ++kw)
        acc += srow[kh * 200 + w + kw] * cw[f * 21 + kh * 3 + kw];
    float v = (acc + cb[f]) * g1[f] + b1[f];
    v = v > 0.f ? v : 0.f;
    x1[(size_t)b * 39600 + idx] = f2b(v);
  }
}

// ---------------- fc GEMM (MFMA): (B x K) @ (K x 208), 8-way K-split, atomic partials into Y ----------------

#define FC_LDA 68   // u32 per LDS A row (= 136 bf16; 128 data + pad)

__global__ __launch_bounds__(256) void k_fcgemm(const unsigned int* __restrict__ X32,
                                                const unsigned short* __restrict__ Wpk,
                                                float* __restrict__ Y, int Mtot, int KU32, int ktseg) {
  __shared__ unsigned int Alds[64 * FC_LDA];
  int tid = threadIdx.x;
  int lane = tid & 63, wid = tid >> 6;
  int mblk = blockIdx.x >> 3;
  int ks = blockIdx.x & 7;
  int row0 = mblk * 64;
  int kt_beg = ks * ktseg, kt_end = kt_beg + ktseg;

  int nt0 = (wid == 0) ? 0 : (wid == 1) ? 4 : (wid == 2) ? 7 : 10;
  int ntc = (wid == 0) ? 4 : 3;

  f32x4 acc[4][4];
#pragma unroll
  for (int a = 0; a < 4; ++a)
#pragma unroll
    for (int b = 0; b < 4; ++b) acc[a][b] = (f32x4){0.f, 0.f, 0.f, 0.f};

  for (int c0 = kt_beg; c0 < kt_end; c0 += 4) {
    __syncthreads();
    for (int u = tid; u < 64 * FC_LDA; u += 256) {
      int r = u / FC_LDA, c = u - r * FC_LDA;
      unsigned int val = 0;
      int gr = row0 + r;
      if (c < 64 && gr < Mtot) {
        int cu = c0 * 16 + c;
        if (cu < KU32) val = X32[(size_t)gr * KU32 + cu];
      }
      Alds[u] = val;
    }
    __syncthreads();
#pragma unroll
    for (int kkt = 0; kkt < 4; ++kkt) {
      int ktg = c0 + kkt;
      if (ktg < kt_end) {
        s16x8 afr[4];
#pragma unroll
        for (int rt = 0; rt < 4; ++rt) {
          int row = rt * 16 + (lane & 15);
          afr[rt] = *(const s16x8*)((const unsigned short*)Alds + row * (FC_LDA * 2) + kkt * 32 + ((lane >> 4) << 3));
        }
#pragma unroll
        for (int ln = 0; ln < 4; ++ln) {
          if (ln < ntc) {
            int nt = nt0 + ln;
            s16x8 bfr = *(const s16x8*)(Wpk + ((size_t)ktg * 13 + nt) * 512 + lane * 8);
#pragma unroll
            for (int rt = 0; rt < 4; ++rt)
              acc[rt][ln] = __builtin_amdgcn_mfma_f32_16x16x32_bf16(afr[rt], bfr, acc[rt][ln], 0, 0, 0);
          }
        }
      }
    }
  }
#pragma unroll
  for (int rt = 0; rt < 4; ++rt) {
#pragma unroll
    for (int ln = 0; ln < 4; ++ln) {
      if (ln < ntc) {
        int j = (nt0 + ln) * 16 + (lane & 15);
        if (j < D) {
#pragma unroll
          for (int r = 0; r < 4; ++r) {
            int b = row0 + rt * 16 + ((lane >> 4) << 2) + r;
            if (b < Mtot) atomicAdd(&Y[(size_t)b * 208 + j], acc[rt][ln][r]);
          }
        }
      }
    }
  }
}

// ---------------- fc_b + bn2 + relu + row-sum -> out ----------------

__global__ __launch_bounds__(256) void k_epilogue(const float* __restrict__ Y, const float* __restrict__ fc_b,
                                                  const float* __restrict__ bn2_g, const float* __restrict__ bn2_b,
                                                  float* __restrict__ out) {
  __shared__ float red[4];
  int b = blockIdx.x, tid = threadIdx.x;
  float v = 0.f;
  if (tid < D) {
    float y = Y[(size_t)b * 208 + tid] + fc_b[tid];
    y = y * (bn2_g[tid] * BNS_F) + bn2_b[tid];
    v = y > 0.f ? y : 0.f;
  }
#pragma unroll
  for (int o = 32; o > 0; o >>= 1) v += __shfl_down(v, o);
  if ((tid & 63) == 0) red[tid >> 6] = v;
  __syncthreads();
  if (tid == 0) out[b] = red[0] + red[1] + red[2] + red[3];
}

// ---------------- host launch ----------------

extern "C" void kernel_launch(void* const* d_in, const int* in_sizes, int n_in,
                              void* d_out, int out_size, void* d_ws, size_t ws_size,
                              hipStream_t stream) {
  const float* E          = (const float*)d_in[0];
  const float* R          = (const float*)d_in[1];
  const float* w_alle     = (const float*)d_in[2];
  const float* w_addpos   = (const float*)d_in[3];
  const float* w_alleandr = (const float*)d_in[4];
  const float* w_rel      = (const float*)d_in[5];
  const float* conv_w     = (const float*)d_in[6];
  const float* conv_b     = (const float*)d_in[7];
  const float* fc_w       = (const float*)d_in[8];
  const float* fc_b       = (const float*)d_in[9];
  const float* bnmp_g     = (const float*)d_in[10];
  const float* bnmp_b     = (const float*)d_in[11];
  const float* bn0_g      = (const float*)d_in[12];
  const float* bn0_b      = (const float*)d_in[13];
  const float* bn1_g      = (const float*)d_in[14];
  const float* bn1_b      = (const float*)d_in[15];
  const float* bn2_g      = (const float*)d_in[16];
  const float* bn2_b      = (const float*)d_in[17];
  const float* ms         = (const float*)d_in[18];
  const int* hyperedge    = (const int*)d_in[19];
  const int* edge_index   = (const int*)d_in[20];
  const int* edge_type    = (const int*)d_in[21];
  const int* r_idx        = (const int*)d_in[22];
  const int* e1 = (const int*)d_in[23];
  const int* e2 = (const int*)d_in[24];
  const int* e3 = (const int*)d_in[25];
  const int* e4 = (const int*)d_in[26];
  const int* e5 = (const int*)d_in[27];
  const int* e6 = (const int*)d_in[28];
  const int* entp = (const int*)d_in[29];

  const int Nn    = in_sizes[0] / D;        // 50006
  const int NR    = in_sizes[1] / D;        // 2000
  const int Hh    = in_sizes[19] / 7;       // 100000
  const int NEdge = in_sizes[21];           // 600000
  const int B     = in_sizes[22];           // 2048
  const int K_fc  = in_sizes[8] / D;        // 39600
  const int KT_fc = (K_fc + 31) / 32;       // 1238
  const int KT_pad = ((KT_fc + 7) / 8) * 8; // 1240
  const int ktseg = KT_pad / 8;             // 155
  const int KU32  = K_fc / 2;               // 19800

  const int* esrc = edge_index;
  const int* edst = edge_index + NEdge;

  char* W = (char*)d_ws;
  size_t off = 0;
  auto alloc = [&](size_t bytes) { size_t o = off; off += (bytes + 255) & ~(size_t)255; return o; };
  size_t o_Ebf  = alloc((size_t)Nn * D * 2);
  size_t o_Ubf  = alloc((size_t)Hh * D * 2);
  size_t o_S    = alloc((size_t)Nn * 400 * 4);
  size_t o_outE = alloc((size_t)Nn * D * 4);
  size_t regionA_end = off;
  size_t x1_bytes = (size_t)B * (size_t)K_fc * 2;   // aliases region A (all dead by then)
  size_t o_stk  = alloc((size_t)B * 1400 * 4);
  size_t o_Y    = alloc((size_t)B * 208 * 4);
  size_t o_outR = alloc((size_t)NR * D * 4);
  size_t o_need = alloc(((size_t)Nn + 1) * 4);      // needed[Nn] + cnt at [Nn]
  size_t o_list = alloc((size_t)(6 * B + 16) * 4);
  size_t o_Wcc  = alloc((size_t)400 * D * 4);
  size_t o_WpkU = alloc((size_t)546 * 512 * 2);
  size_t o_Wfc  = alloc((size_t)KT_pad * 13 * 512 * 2);
  if (ws_size < off || x1_bytes > regionA_end) return;  // insufficient workspace -> fail visibly

  unsigned short* Ebf  = (unsigned short*)(W + o_Ebf);
  unsigned short* Ubf  = (unsigned short*)(W + o_Ubf);
  float*          S    = (float*)(W + o_S);
  float*          outE = (float*)(W + o_outE);
  unsigned short* x1   = (unsigned short*)W;        // alias
  float*          stk  = (float*)(W + o_stk);
  float*          Y    = (float*)(W + o_Y);
  float*          outR = (float*)(W + o_outR);
  int*            needed = (int*)(W + o_need);
  int*            cnt    = needed + Nn;
  int*            list   = (int*)(W + o_list);
  float*          Wcc    = (float*)(W + o_Wcc);
  unsigned short* WpkU   = (unsigned short*)(W + o_WpkU);
  unsigned short* Wfc    = (unsigned short*)(W + o_Wfc);

  // zero-init (ws is poisoned before every call)
  hipMemsetAsync(S, 0, (size_t)Nn * 400 * 4, stream);
  hipMemsetAsync(needed, 0, ((size_t)Nn + 1) * 4, stream);
  hipMemsetAsync(Y, 0, (size_t)B * 208 * 4, stream);

  // prep
  hipLaunchKernelGGL(k_cvt_bf16, dim3(4096), dim3(256), 0, stream, E, Ebf, Nn * D);
  hipLaunchKernelGGL(k_prep_w1p, dim3(546), dim3(64), 0, stream, E, w_alle, entp, WpkU);
  hipLaunchKernelGGL(k_prep_wcc, dim3(400), dim3(256), 0, stream, w_alleandr, w_addpos, Wcc);
  hipLaunchKernelGGL(k_prep_wfc, dim3(KT_pad * 13), dim3(64), 0, stream, fc_w, Wfc, K_fc);
  hipLaunchKernelGGL(k_mask, dim3((6 * B + 6 + 255) / 256), dim3(256), 0, stream,
                     e1, e2, e3, e4, e5, e6, entp, needed, B);
  hipLaunchKernelGGL(k_compact, dim3((Nn + 255) / 256), dim3(256), 0, stream, needed, list, cnt, Nn);

  // main pipeline
  hipLaunchKernelGGL(k_ugemm, dim3((Hh + 63) / 64), dim3(256), 0, stream,
                     (const unsigned int*)Ebf, R, hyperedge, WpkU, Ubf, Hh);
  hipLaunchKernelGGL(k_scatter, dim3((NEdge + 3) / 4), dim3(256), 0, stream,
                     esrc, edst, edge_type, needed, Ubf, E, S, NEdge);
  hipLaunchKernelGGL(k_aggout, dim3((6 * B + 6 + 7) / 8), dim3(256), 0, stream,
                     list, cnt, S, Wcc, E, bnmp_g, bnmp_b, outE);
  hipLaunchKernelGGL(k_outr, dim3(NR), dim3(256), 0, stream, R, w_rel, outR);
  hipLaunchKernelGGL(k_stk, dim3(B), dim3(256), 0, stream,
                     outE, outR, r_idx, e1, e2, e3, e4, e5, e6, ms, entp, bn0_g, bn0_b, stk);
  hipLaunchKernelGGL(k_conv, dim3(B), dim3(256), 0, stream, stk, conv_w, conv_b, bn1_g, bn1_b, x1);
  hipLaunchKernelGGL(k_fcgemm, dim3(((B + 63) / 64) * 8), dim3(256), 0, stream,
                     (const unsigned int*)x1, Wfc, Y, B, KU32, ktseg);
  hipLaunchKernelGGL(k_epilogue, dim3(B), dim3(256), 0, stream, Y, fc_b, bn2_g, bn2_b, (float*)d_out);
}

// Round 3
// 1227.465 us; speedup vs baseline: 1.2224x; 1.2224x over previous
//
#include <hip/hip_runtime.h>

#define D 200
#define FEAT 39600
#define BNS_F 0.9999950000374997f   // 1/sqrt(1+1e-5)
#define FC_NSPLIT 10

typedef float f32x4 __attribute__((ext_vector_type(4)));
typedef short s16x8 __attribute__((ext_vector_type(8)));
typedef unsigned int u32;

static __device__ __forceinline__ unsigned short f2b(float f) {
  union { float f; unsigned u; } v; v.f = f;
  return (unsigned short)((v.u + 0x7FFFu + ((v.u >> 16) & 1u)) >> 16);
}
static __device__ __forceinline__ float b2f(unsigned short h) {
  union { unsigned u; float f; } v; v.u = ((unsigned)h) << 16;
  return v.f;
}
static __device__ __forceinline__ void gload_lds16(const void* g, void* l) {
  __builtin_amdgcn_global_load_lds((const __attribute__((address_space(1))) u32*)g,
                                   (__attribute__((address_space(3))) u32*)l, 16, 0, 0);
}

// ---------------- prep kernels ----------------

__global__ __launch_bounds__(256) void k_cvt_bf16(const float* __restrict__ src,
                                                  unsigned short* __restrict__ dst, int n) {
  int stride = gridDim.x * 256;
  for (int i = blockIdx.x * 256 + threadIdx.x; i < n; i += stride) dst[i] = f2b(src[i]);
}

// W1p[k][i][j] = 0.5 * pos[k][i] * w_alle[k*200+i][j], packed in MFMA B-fragment order.
__global__ __launch_bounds__(64) void k_prep_w1p(const float* __restrict__ E,
                                                 const float* __restrict__ w_alle,
                                                 const int* __restrict__ entp,
                                                 unsigned short* __restrict__ Wpk) {
  int blk = blockIdx.x;
  int lane = threadIdx.x;
  int nt = blk % 13; int rem = blk / 13; int kt = rem % 7; int ks = rem / 7;
  int ent = *entp;
  int j = nt * 16 + (lane & 15);
  unsigned short* p = Wpk + (size_t)blk * 512 + lane * 8;
#pragma unroll
  for (int t = 0; t < 8; ++t) {
    int kk = kt * 32 + ((lane >> 4) << 3) + t;
    float v = 0.f;
    if (kk < D && j < D)
      v = 0.5f * E[(size_t)(ent + ks) * D + kk] * w_alle[(size_t)(ks * D + kk) * D + j];
    p[t] = f2b(v);
  }
}

// Wcc (400 x 200) fp32: rows 0..199 = w_alleandr @ w_addpos[0:200], rows 200..399 = w_addpos[200:400]
__global__ __launch_bounds__(256) void k_prep_wcc(const float* __restrict__ w_alleandr,
                                                  const float* __restrict__ w_addpos,
                                                  float* __restrict__ Wcc) {
  int t = blockIdx.x;
  int j = threadIdx.x;
  if (j >= D) return;
  float v;
  if (t < D) {
    float acc = 0.f;
    for (int u = 0; u < D; ++u) acc += w_alleandr[t * D + u] * w_addpos[u * D + j];
    v = acc;
  } else {
    v = w_addpos[t * D + j];
  }
  Wcc[t * D + j] = v;
}

// fc_w (K x 200) -> packed bf16 fragments [kt][nt][512]
__global__ __launch_bounds__(64) void k_prep_wfc(const float* __restrict__ fc_w,
                                                 unsigned short* __restrict__ Wpk, int K) {
  int blk = blockIdx.x;   // kt*13 + nt
  int lane = threadIdx.x;
  int nt = blk % 13; int kt = blk / 13;
  int j = nt * 16 + (lane & 15);
  unsigned short* p = Wpk + (size_t)blk * 512 + lane * 8;
#pragma unroll
  for (int t = 0; t < 8; ++t) {
    int kk = kt * 32 + ((lane >> 4) << 3) + t;
    float v = (kk < K && j < D) ? fc_w[(size_t)kk * D + j] : 0.f;
    p[t] = f2b(v);
  }
}

// ---------------- needed-node mask + compaction ----------------

__global__ __launch_bounds__(256) void k_mask(const int* __restrict__ e1, const int* __restrict__ e2,
                                              const int* __restrict__ e3, const int* __restrict__ e4,
                                              const int* __restrict__ e5, const int* __restrict__ e6,
                                              const int* __restrict__ entp,
                                              int* __restrict__ needed, int B) {
  int t = blockIdx.x * 256 + threadIdx.x;
  int total = 6 * B;
  if (t < total) {
    int k = t / B, b = t - k * B;
    const int* p = (k == 0) ? e1 : (k == 1) ? e2 : (k == 2) ? e3 : (k == 3) ? e4 : (k == 4) ? e5 : e6;
    needed[p[b]] = 1;
  } else if (t < total + 6) {
    needed[*entp + (t - total)] = 1;
  }
}

__global__ __launch_bounds__(256) void k_compact(const int* __restrict__ needed,
                                                 int* __restrict__ list, int* __restrict__ cnt, int Nn) {
  int n = blockIdx.x * 256 + threadIdx.x;
  if (n < Nn && needed[n]) {
    int p = atomicAdd(cnt, 1);
    list[p] = n;
  }
}

// ---------------- U GEMM (MFMA) ----------------

#define U_LDA 116

__global__ __launch_bounds__(256) void k_ugemm(const u32* __restrict__ Ebf32,
                                               const float* __restrict__ Rm,
                                               const int* __restrict__ he,
                                               const unsigned short* __restrict__ Wpk,
                                               unsigned short* __restrict__ Ubf, int H) {
  __shared__ u32 Alds[64 * U_LDA];
  __shared__ int helds[64][7];
  int tid = threadIdx.x;
  int lane = tid & 63, wid = tid >> 6;
  int h0 = blockIdx.x * 64;

  for (int u = tid; u < 64 * 7; u += 256) {
    int r = u / 7, c = u - r * 7;
    int hg = h0 + r; if (hg >= H) hg = H - 1;
    helds[r][c] = he[(size_t)hg * 7 + c];
  }

  int nt0 = (wid == 0) ? 0 : (wid == 1) ? 4 : (wid == 2) ? 7 : 10;
  int ntc = (wid == 0) ? 4 : 3;

  f32x4 acc[4][4];
#pragma unroll
  for (int a = 0; a < 4; ++a)
#pragma unroll
    for (int b = 0; b < 4; ++b) acc[a][b] = (f32x4){0.f, 0.f, 0.f, 0.f};

  for (int ks = 0; ks < 6; ++ks) {
    __syncthreads();
    for (int u = tid; u < 64 * U_LDA; u += 256) {
      int r = u / U_LDA, c = u - r * U_LDA;
      u32 val = 0;
      if (c < 100) {
        int eidx = helds[r][1 + ks];
        val = Ebf32[(size_t)eidx * 100 + c];
      }
      Alds[u] = val;
    }
    __syncthreads();
#pragma unroll
    for (int kt = 0; kt < 7; ++kt) {
      s16x8 afr[4];
#pragma unroll
      for (int rt = 0; rt < 4; ++rt) {
        int row = rt * 16 + (lane & 15);
        afr[rt] = *(const s16x8*)((const unsigned short*)Alds + row * (U_LDA * 2) + kt * 32 + ((lane >> 4) << 3));
      }
#pragma unroll
      for (int ln = 0; ln < 4; ++ln) {
        if (ln < ntc) {
          int nt = nt0 + ln;
          s16x8 bfr = *(const s16x8*)(Wpk + ((size_t)((ks * 7 + kt) * 13 + nt)) * 512 + lane * 8);
#pragma unroll
          for (int rt = 0; rt < 4; ++rt)
            acc[rt][ln] = __builtin_amdgcn_mfma_f32_16x16x32_bf16(afr[rt], bfr, acc[rt][ln], 0, 0, 0);
        }
      }
    }
  }
#pragma unroll
  for (int rt = 0; rt < 4; ++rt) {
#pragma unroll
    for (int ln = 0; ln < 4; ++ln) {
      if (ln < ntc) {
        int j = (nt0 + ln) * 16 + (lane & 15);
        if (j < D) {
#pragma unroll
          for (int r = 0; r < 4; ++r) {
            int row = rt * 16 + ((lane >> 4) << 2) + r;
            int h = h0 + row;
            if (h < H) {
              float v = acc[rt][ln][r] + 0.5f * Rm[(size_t)helds[row][0] * D + j];
              Ubf[(size_t)h * D + j] = f2b(v);
            }
          }
        }
      }
    }
  }
}

// ---------------- edge scatter ----------------

__global__ __launch_bounds__(256) void k_scatter(const int* __restrict__ esrc, const int* __restrict__ edst,
                                                 const int* __restrict__ etyp, const int* __restrict__ needed,
                                                 const unsigned short* __restrict__ Ubf,
                                                 const float* __restrict__ E,
                                                 float* __restrict__ S, int NEdge) {
  int wave = blockIdx.x * 4 + (threadIdx.x >> 6);
  int lane = threadIdx.x & 63;
  if (wave >= NEdge) return;
  int s = esrc[wave];
  if (!needed[s]) return;
  int et = etyp[wave];
  int dd = edst[wave];
  float* Sr = S + (size_t)s * 400;
  for (int c = lane; c < 400; c += 64) {
    float v = (c < D) ? b2f(Ubf[(size_t)et * D + c]) : E[(size_t)dd * D + (c - D)];
    atomicAdd(Sr + c, v);
  }
}

// ---------------- agg -> outE for needed nodes ----------------

__global__ __launch_bounds__(256) void k_aggout(const int* __restrict__ list, const int* __restrict__ cnt,
                                                const float* __restrict__ S, const float* __restrict__ Wcc,
                                                const float* __restrict__ E,
                                                const float* __restrict__ bnmp_g, const float* __restrict__ bnmp_b,
                                                float* __restrict__ outE) {
  __shared__ float Slds[8][400];
  __shared__ int nodes[8];
  int tid = threadIdx.x;
  int base = blockIdx.x * 8;
  int count = *cnt;
  if (base >= count) return;
  if (tid < 8) nodes[tid] = (base + tid < count) ? list[base + tid] : -1;
  __syncthreads();
  for (int u = tid; u < 8 * 400; u += 256) {
    int m = u / 400, t = u - m * 400;
    int n = nodes[m];
    Slds[m][t] = (n >= 0) ? S[(size_t)n * 400 + t] : 0.f;
  }
  __syncthreads();
  int j = tid;
  if (j >= D) return;
  float acc[8] = {0.f, 0.f, 0.f, 0.f, 0.f, 0.f, 0.f, 0.f};
  for (int t = 0; t < 400; ++t) {
    float w = Wcc[t * D + j];
#pragma unroll
    for (int m = 0; m < 8; ++m) acc[m] += Slds[m][t] * w;
  }
  float gs = bnmp_g[j] * BNS_F;
  float gb = bnmp_b[j];
#pragma unroll
  for (int m = 0; m < 8; ++m) {
    int n = nodes[m];
    if (n >= 0) {
      float v = 0.5f * acc[m] + 0.5f * E[(size_t)n * D + j];
      outE[(size_t)n * D + j] = tanhf(v * gs + gb);
    }
  }
}

// ---------------- outR = R @ w_rel ----------------

__global__ __launch_bounds__(256) void k_outr(const float* __restrict__ Rm, const float* __restrict__ w_rel,
                                              float* __restrict__ outR) {
  int r = blockIdx.x; int j = threadIdx.x;
  if (j >= D) return;
  float acc = 0.f;
  for (int t = 0; t < D; ++t) acc += Rm[(size_t)r * D + t] * w_rel[t * D + j];
  outR[(size_t)r * D + j] = acc;
}

// ---------------- build stk ----------------

__global__ __launch_bounds__(256) void k_stk(const float* __restrict__ outE, const float* __restrict__ outR,
                                             const int* __restrict__ r_idx,
                                             const int* __restrict__ e1, const int* __restrict__ e2,
                                             const int* __restrict__ e3, const int* __restrict__ e4,
                                             const int* __restrict__ e5, const int* __restrict__ e6,
                                             const float* __restrict__ ms, const int* __restrict__ entp,
                                             const float* __restrict__ bn0_g, const float* __restrict__ bn0_b,
                                             float* __restrict__ stk) {
  int b = blockIdx.x; int j = threadIdx.x;
  if (j >= D) return;
  int ent = *entp;
  float s0 = bn0_g[0] * BNS_F, b0 = bn0_b[0];
  float* out = stk + (size_t)b * 1400;
  out[j] = outR[(size_t)r_idx[b] * D + j] * s0 + b0;
#pragma unroll
  for (int k = 0; k < 6; ++k) {
    const int* ep = (k == 0) ? e1 : (k == 1) ? e2 : (k == 2) ? e3 : (k == 3) ? e4 : (k == 4) ? e5 : e6;
    float q = outE[(size_t)(ent + k) * D + j];
    float v = outE[(size_t)ep[b] * D + j] * q * ms[(size_t)b * 6 + k];
    out[(1 + k) * D + j] = v * s0 + b0;
  }
}

// ---------------- conv + bn1 + relu -> x1 bf16 (B x KPAD, zero-padded) ----------------

__global__ __launch_bounds__(256) void k_conv(const float* __restrict__ stk, const float* __restrict__ conv_w,
                                              const float* __restrict__ conv_b, const float* __restrict__ bn1_g,
                                              const float* __restrict__ bn1_b, unsigned short* __restrict__ x1,
                                              int KPAD) {
  __shared__ float srow[1400];
  __shared__ float cw[4200];
  __shared__ float cb[200], g1[200], b1[200];
  int b = blockIdx.x, tid = threadIdx.x;
  for (int u = tid; u < 1400; u += 256) srow[u] = stk[(size_t)b * 1400 + u];
  for (int u = tid; u < 4200; u += 256) cw[u] = conv_w[u];
  if (tid < 200) { cb[tid] = conv_b[tid]; g1[tid] = bn1_g[tid] * BNS_F; b1[tid] = bn1_b[tid]; }
  __syncthreads();
  for (int idx = tid; idx < FEAT; idx += 256) {
    int f = idx / 198, w = idx - f * 198;
    float acc = 0.f;
#pragma unroll
    for (int kh = 0; kh < 7; ++kh)
#pragma unroll
      for (int kw = 0; kw < 3; ++kw)
        acc += srow[kh * 200 + w + kw] * cw[f * 21 + kh * 3 + kw];
    float v = (acc + cb[f]) * g1[f] + b1[f];
    v = v > 0.f ? v : 0.f;
    x1[(size_t)b * KPAD + idx] = f2b(v);
  }
  for (int idx = FEAT + tid; idx < KPAD; idx += 256) x1[(size_t)b * KPAD + idx] = 0;
}

// ---------------- fc GEMM: M-tile 32, K-split, global_load_lds staging, XOR swizzle ----------------
// LDS layout per buffer: [32 rows][64 u32] linear, 16B chunks XOR-swizzled: phys = logical ^ (row&7)

__global__ __launch_bounds__(256) void k_fcgemm(const u32* __restrict__ X32,
                                                const unsigned short* __restrict__ Wpk,
                                                float* __restrict__ Ypart,
                                                int Mtot, int KU32, int KCH, int chPerSeg) {
  __shared__ u32 Alds[2][2048];
  int tid = threadIdx.x;
  int lane = tid & 63, wid = tid >> 6;
  int mblks = gridDim.x / FC_NSPLIT;
  int seg = blockIdx.x / mblks;
  int mblk = blockIdx.x - seg * mblks;
  int row0 = mblk * 32;
  int ch0 = seg * chPerSeg;
  int nCh = KCH - ch0; if (nCh > chPerSeg) nCh = chPerSeg;
  if (nCh <= 0) return;

  int nt0 = (wid == 0) ? 0 : (wid == 1) ? 4 : (wid == 2) ? 7 : 10;
  int ntc = (wid == 0) ? 4 : 3;

  f32x4 acc[2][4];
#pragma unroll
  for (int a = 0; a < 2; ++a)
#pragma unroll
    for (int b = 0; b < 4; ++b) acc[a][b] = (f32x4){0.f, 0.f, 0.f, 0.f};

  // per-thread staging source precompute: thread covers chunks c = tid and tid+256
  int srow0 = tid >> 4;            // c0 row (0..15)
  int spch0 = tid & 15;
  int slch0 = spch0 ^ (srow0 & 7);
  int srow1 = (tid + 256) >> 4;    // rows 16..31
  int spch1 = tid & 15;
  int slch1 = spch1 ^ (srow1 & 7);
  int gr0 = row0 + srow0; if (gr0 >= Mtot) gr0 = Mtot - 1;
  int gr1 = row0 + srow1; if (gr1 >= Mtot) gr1 = Mtot - 1;
  const u32* src0 = X32 + (size_t)gr0 * KU32 + slch0 * 4;
  const u32* src1 = X32 + (size_t)gr1 * KU32 + slch1 * 4;

#define STAGE(bsel, ch)                                                        \
  do {                                                                         \
    gload_lds16(src0 + (size_t)(ch) * 64, &Alds[bsel][wid * 256]);             \
    gload_lds16(src1 + (size_t)(ch) * 64, &Alds[bsel][1024 + wid * 256]);      \
  } while (0)

  STAGE(0, ch0);
  __syncthreads();

  for (int i = 0; i < nCh; ++i) {
    if (i + 1 < nCh) STAGE((i + 1) & 1, ch0 + i + 1);
    const unsigned short* buf = (const unsigned short*)Alds[i & 1];
    int ch = ch0 + i;
#pragma unroll
    for (int kkt = 0; kkt < 4; ++kkt) {
      s16x8 afr[2];
#pragma unroll
      for (int rt = 0; rt < 2; ++rt) {
        int row = rt * 16 + (lane & 15);
        int pch = ((kkt << 2) + (lane >> 4)) ^ (row & 7);
        afr[rt] = *(const s16x8*)(buf + row * 128 + pch * 8);
      }
      size_t ktg = (size_t)(ch * 4 + kkt);
#pragma unroll
      for (int ln = 0; ln < 4; ++ln) {
        if (ln < ntc) {
          s16x8 bfr = *(const s16x8*)(Wpk + (ktg * 13 + nt0 + ln) * 512 + lane * 8);
          acc[0][ln] = __builtin_amdgcn_mfma_f32_16x16x32_bf16(afr[0], bfr, acc[0][ln], 0, 0, 0);
          acc[1][ln] = __builtin_amdgcn_mfma_f32_16x16x32_bf16(afr[1], bfr, acc[1][ln], 0, 0, 0);
        }
      }
    }
    __syncthreads();
  }
#undef STAGE

  float* Yp = Ypart + (size_t)seg * Mtot * 208;
#pragma unroll
  for (int rt = 0; rt < 2; ++rt) {
#pragma unroll
    for (int ln = 0; ln < 4; ++ln) {
      if (ln < ntc) {
        int j = (nt0 + ln) * 16 + (lane & 15);
#pragma unroll
        for (int r = 0; r < 4; ++r) {
          int b = row0 + rt * 16 + ((lane >> 4) << 2) + r;
          if (b < Mtot) Yp[(size_t)b * 208 + j] = acc[rt][ln][r];
        }
      }
    }
  }
}

// ---------------- reduce partials + fc_b + bn2 + relu + row-sum -> out ----------------

__global__ __launch_bounds__(256) void k_epilogue(const float* __restrict__ Ypart, const float* __restrict__ fc_b,
                                                  const float* __restrict__ bn2_g, const float* __restrict__ bn2_b,
                                                  float* __restrict__ out, int Mtot) {
  __shared__ float red[4];
  int b = blockIdx.x, tid = threadIdx.x;
  float v = 0.f;
  if (tid < D) {
    float y = fc_b[tid];
#pragma unroll
    for (int s = 0; s < FC_NSPLIT; ++s) y += Ypart[((size_t)s * Mtot + b) * 208 + tid];
    y = y * (bn2_g[tid] * BNS_F) + bn2_b[tid];
    v = y > 0.f ? y : 0.f;
  }
#pragma unroll
  for (int o = 32; o > 0; o >>= 1) v += __shfl_down(v, o);
  if ((tid & 63) == 0) red[tid >> 6] = v;
  __syncthreads();
  if (tid == 0) out[b] = red[0] + red[1] + red[2] + red[3];
}

// ---------------- host launch ----------------

extern "C" void kernel_launch(void* const* d_in, const int* in_sizes, int n_in,
                              void* d_out, int out_size, void* d_ws, size_t ws_size,
                              hipStream_t stream) {
  const float* E          = (const float*)d_in[0];
  const float* R          = (const float*)d_in[1];
  const float* w_alle     = (const float*)d_in[2];
  const float* w_addpos   = (const float*)d_in[3];
  const float* w_alleandr = (const float*)d_in[4];
  const float* w_rel      = (const float*)d_in[5];
  const float* conv_w     = (const float*)d_in[6];
  const float* conv_b     = (const float*)d_in[7];
  const float* fc_w       = (const float*)d_in[8];
  const float* fc_b       = (const float*)d_in[9];
  const float* bnmp_g     = (const float*)d_in[10];
  const float* bnmp_b     = (const float*)d_in[11];
  const float* bn0_g      = (const float*)d_in[12];
  const float* bn0_b      = (const float*)d_in[13];
  const float* bn1_g      = (const float*)d_in[14];
  const float* bn1_b      = (const float*)d_in[15];
  const float* bn2_g      = (const float*)d_in[16];
  const float* bn2_b      = (const float*)d_in[17];
  const float* ms         = (const float*)d_in[18];
  const int* hyperedge    = (const int*)d_in[19];
  const int* edge_index   = (const int*)d_in[20];
  const int* edge_type    = (const int*)d_in[21];
  const int* r_idx        = (const int*)d_in[22];
  const int* e1 = (const int*)d_in[23];
  const int* e2 = (const int*)d_in[24];
  const int* e3 = (const int*)d_in[25];
  const int* e4 = (const int*)d_in[26];
  const int* e5 = (const int*)d_in[27];
  const int* e6 = (const int*)d_in[28];
  const int* entp = (const int*)d_in[29];

  const int Nn    = in_sizes[0] / D;        // 50006
  const int NR    = in_sizes[1] / D;        // 2000
  const int Hh    = in_sizes[19] / 7;       // 100000
  const int NEdge = in_sizes[21];           // 600000
  const int B     = in_sizes[22];           // 2048
  const int K_fc  = in_sizes[8] / D;        // 39600
  const int KCH   = (K_fc + 127) / 128;     // 310 chunks of 128
  const int KPAD  = KCH * 128;              // 39680
  const int KU32  = KPAD / 2;               // 19840
  const int chPerSeg = (KCH + FC_NSPLIT - 1) / FC_NSPLIT;  // 31
  const int KT_tot = KCH * 4;               // 1240 kt tiles for Wfc packing
  const int mblks = (B + 31) / 32;          // 64

  const int* esrc = edge_index;
  const int* edst = edge_index + NEdge;

  char* W = (char*)d_ws;
  size_t off = 0;
  auto alloc = [&](size_t bytes) { size_t o = off; off += (bytes + 255) & ~(size_t)255; return o; };
  // persistent small buffers first
  size_t o_Wfc  = alloc((size_t)KT_tot * 13 * 512 * 2);
  size_t o_WpkU = alloc((size_t)546 * 512 * 2);
  size_t o_Wcc  = alloc((size_t)400 * D * 4);
  size_t o_need = alloc(((size_t)Nn + 1) * 4);
  size_t o_list = alloc((size_t)(6 * B + 16) * 4);
  size_t o_outR = alloc((size_t)NR * D * 4);
  size_t o_stk  = alloc((size_t)B * 1400 * 4);
  // region A (big transients; later aliased by x1 + Ypart)
  size_t o_A    = off;
  size_t o_Ebf  = alloc((size_t)Nn * D * 2);
  size_t o_Ubf  = alloc((size_t)Hh * D * 2);
  size_t o_S    = alloc((size_t)Nn * 400 * 4);
  size_t o_outE = alloc((size_t)Nn * D * 4);
  size_t regionA_end = off;

  size_t x1_bytes = (size_t)B * KPAD * 2;
  size_t o_x1 = o_A;
  size_t o_Yp = o_A + ((x1_bytes + 255) & ~(size_t)255);
  size_t yp_bytes = (size_t)FC_NSPLIT * B * 208 * 4;
  if (ws_size < off) return;
  if (o_Yp + yp_bytes > regionA_end) return;

  unsigned short* Ebf  = (unsigned short*)(W + o_Ebf);
  unsigned short* Ubf  = (unsigned short*)(W + o_Ubf);
  float*          S    = (float*)(W + o_S);
  float*          outE = (float*)(W + o_outE);
  unsigned short* x1   = (unsigned short*)(W + o_x1);
  float*          Ypart= (float*)(W + o_Yp);
  float*          stk  = (float*)(W + o_stk);
  float*          outR = (float*)(W + o_outR);
  int*            needed = (int*)(W + o_need);
  int*            cnt    = needed + Nn;
  int*            list   = (int*)(W + o_list);
  float*          Wcc    = (float*)(W + o_Wcc);
  unsigned short* WpkU   = (unsigned short*)(W + o_WpkU);
  unsigned short* Wfc    = (unsigned short*)(W + o_Wfc);

  hipMemsetAsync(S, 0, (size_t)Nn * 400 * 4, stream);
  hipMemsetAsync(needed, 0, ((size_t)Nn + 1) * 4, stream);

  // prep
  hipLaunchKernelGGL(k_cvt_bf16, dim3(4096), dim3(256), 0, stream, E, Ebf, Nn * D);
  hipLaunchKernelGGL(k_prep_w1p, dim3(546), dim3(64), 0, stream, E, w_alle, entp, WpkU);
  hipLaunchKernelGGL(k_prep_wcc, dim3(400), dim3(256), 0, stream, w_alleandr, w_addpos, Wcc);
  hipLaunchKernelGGL(k_prep_wfc, dim3(KT_tot * 13), dim3(64), 0, stream, fc_w, Wfc, K_fc);
  hipLaunchKernelGGL(k_mask, dim3((6 * B + 6 + 255) / 256), dim3(256), 0, stream,
                     e1, e2, e3, e4, e5, e6, entp, needed, B);
  hipLaunchKernelGGL(k_compact, dim3((Nn + 255) / 256), dim3(256), 0, stream, needed, list, cnt, Nn);

  // main pipeline
  hipLaunchKernelGGL(k_ugemm, dim3((Hh + 63) / 64), dim3(256), 0, stream,
                     (const u32*)Ebf, R, hyperedge, WpkU, Ubf, Hh);
  hipLaunchKernelGGL(k_scatter, dim3((NEdge + 3) / 4), dim3(256), 0, stream,
                     esrc, edst, edge_type, needed, Ubf, E, S, NEdge);
  hipLaunchKernelGGL(k_aggout, dim3((6 * B + 6 + 7) / 8), dim3(256), 0, stream,
                     list, cnt, S, Wcc, E, bnmp_g, bnmp_b, outE);
  hipLaunchKernelGGL(k_outr, dim3(NR), dim3(256), 0, stream, R, w_rel, outR);
  hipLaunchKernelGGL(k_stk, dim3(B), dim3(256), 0, stream,
                     outE, outR, r_idx, e1, e2, e3, e4, e5, e6, ms, entp, bn0_g, bn0_b, stk);
  hipLaunchKernelGGL(k_conv, dim3(B), dim3(256), 0, stream, stk, conv_w, conv_b, bn1_g, bn1_b, x1, KPAD);
  hipLaunchKernelGGL(k_fcgemm, dim3(mblks * FC_NSPLIT), dim3(256), 0, stream,
                     (const u32*)x1, Wfc, Ypart, B, KU32, KCH, chPerSeg);
  hipLaunchKernelGGL(k_epilogue, dim3(B), dim3(256), 0, stream, Ypart, fc_b, bn2_g, bn2_b, (float*)d_out, B);
}

// Round 5
// 977.899 us; speedup vs baseline: 1.5344x; 1.2552x over previous
//
#include <hip/hip_runtime.h>

#define D 200
#define FEAT 39600
#define BNS_F 0.9999950000374997f   // 1/sqrt(1+1e-5)
#define FC_NSPLIT 16
#define BHALF 1024

typedef float f32x4 __attribute__((ext_vector_type(4)));
typedef short s16x8 __attribute__((ext_vector_type(8)));
typedef unsigned int u32;

static __device__ __forceinline__ unsigned short f2b(float f) {
  union { float f; unsigned u; } v; v.f = f;
  return (unsigned short)((v.u + 0x7FFFu + ((v.u >> 16) & 1u)) >> 16);
}
static __device__ __forceinline__ float b2f(unsigned short h) {
  union { unsigned u; float f; } v; v.u = ((unsigned)h) << 16;
  return v.f;
}
static __device__ __forceinline__ void gload_lds16(const void* g, void* l) {
  __builtin_amdgcn_global_load_lds((const __attribute__((address_space(1))) u32*)g,
                                   (__attribute__((address_space(3))) u32*)l, 16, 0, 0);
}

// ---------------- prep ----------------

__global__ __launch_bounds__(256) void k_cvt_bf16(const float* __restrict__ src,
                                                  unsigned short* __restrict__ dst, int n) {
  int stride = gridDim.x * 256;
  for (int i = blockIdx.x * 256 + threadIdx.x; i < n; i += stride) dst[i] = f2b(src[i]);
}

// generic small GEMM: C[r][j] = scale * rowscale[r] * sum_u A[r][u] * Bm[u][j]   (K=N=200)
__global__ __launch_bounds__(256) void k_sgemm(const float* __restrict__ A, const float* __restrict__ Bm,
                                               float* __restrict__ C, int M,
                                               const float* __restrict__ rowscale, float scale) {
  __shared__ float A8[8][200];
  int tid = threadIdx.x;
  int m0 = blockIdx.x * 8;
  for (int u = tid; u < 8 * 200; u += 256) {
    int m = u / 200, k = u - m * 200;
    A8[m][k] = (m0 + m < M) ? A[(size_t)(m0 + m) * 200 + k] : 0.f;
  }
  __syncthreads();
  int j = tid; if (j >= 200) return;
  float acc[8] = {0,0,0,0,0,0,0,0};
  for (int u = 0; u < 200; ++u) {
    float b = Bm[u * 200 + j];
#pragma unroll
    for (int m = 0; m < 8; ++m) acc[m] += A8[m][u] * b;
  }
#pragma unroll
  for (int m = 0; m < 8; ++m) {
    int r = m0 + m;
    if (r < M) {
      float s = scale * (rowscale ? rowscale[r] : 1.f);
      C[(size_t)r * 200 + j] = acc[m] * s;
    }
  }
}

// pack B fragments for P-GEMM. cols<600: T[kofs + col/200][kk][col%200]; 600..799 (if useG): w_addpos[200+kk][col-600]
__global__ __launch_bounds__(64) void k_packB(const float* __restrict__ T, const float* __restrict__ w_addpos,
                                              unsigned short* __restrict__ out, int NT, int kofs, int useG) {
  int blk = blockIdx.x;          // kt*NT + nt
  int lane = threadIdx.x;
  int nt = blk % NT, kt = blk / NT;
  int col = nt * 16 + (lane & 15);
  unsigned short* p = out + (size_t)blk * 512 + lane * 8;
#pragma unroll
  for (int t = 0; t < 8; ++t) {
    int kk = kt * 32 + ((lane >> 4) << 3) + t;
    float v = 0.f;
    if (kk < 200) {
      if (col < 600) {
        int k = col / 200;
        v = T[(size_t)((kofs + k) * 200 + kk) * 200 + (col - k * 200)];
      } else if (useG && col < 800) {
        v = w_addpos[(size_t)(200 + kk) * 200 + (col - 600)];
      }
    }
    p[t] = f2b(v);
  }
}

// fc_w (K x 200) -> packed bf16 fragments [kt][nt(13)][512]
__global__ __launch_bounds__(64) void k_prep_wfc(const float* __restrict__ fc_w,
                                                 unsigned short* __restrict__ Wpk, int K) {
  int blk = blockIdx.x;   // kt*13 + nt
  int lane = threadIdx.x;
  int nt = blk % 13; int kt = blk / 13;
  int j = nt * 16 + (lane & 15);
  unsigned short* p = Wpk + (size_t)blk * 512 + lane * 8;
#pragma unroll
  for (int t = 0; t < 8; ++t) {
    int kk = kt * 32 + ((lane >> 4) << 3) + t;
    float v = (kk < K && j < D) ? fc_w[(size_t)kk * D + j] : 0.f;
    p[t] = f2b(v);
  }
}

// ---------------- needed mask / compaction / CSR ----------------

__global__ __launch_bounds__(256) void k_mask(const int* __restrict__ e1, const int* __restrict__ e2,
                                              const int* __restrict__ e3, const int* __restrict__ e4,
                                              const int* __restrict__ e5, const int* __restrict__ e6,
                                              int ent, int* __restrict__ needed, int B) {
  int t = blockIdx.x * 256 + threadIdx.x;
  int total = 6 * B;
  if (t < total) {
    int k = t / B, b = t - k * B;
    const int* p = (k == 0) ? e1 : (k == 1) ? e2 : (k == 2) ? e3 : (k == 3) ? e4 : (k == 4) ? e5 : e6;
    needed[p[b]] = 1;
  } else if (t < total + 6) {
    needed[ent + (t - total)] = 1;
  }
}

__global__ __launch_bounds__(256) void k_compact(int* __restrict__ needed,
                                                 int* __restrict__ list, int* __restrict__ cnt, int Nn) {
  int n = blockIdx.x * 256 + threadIdx.x;
  if (n < Nn && needed[n]) {
    int p = atomicAdd(cnt, 1);
    list[p] = n;
    needed[n] = p + 1;
  }
}

__global__ __launch_bounds__(256) void k_ecount(const int* __restrict__ esrc, const int* __restrict__ needed,
                                                int* __restrict__ deg, int* __restrict__ epos, int NEdge) {
  int e = blockIdx.x * 256 + threadIdx.x;
  if (e >= NEdge) return;
  int sl = needed[esrc[e]];
  epos[e] = (sl > 0) ? atomicAdd(&deg[sl - 1], 1) : -1;
}

__global__ __launch_bounds__(256) void k_prefix(const int* __restrict__ deg, int* __restrict__ rowstart, int nslot) {
  __shared__ int csum[256];
  int t = threadIdx.x;
  int chunk = (nslot + 255) / 256;
  int b = t * chunk;
  int s = 0;
  for (int i = 0; i < chunk; ++i) { int idx = b + i; if (idx < nslot) s += deg[idx]; }
  csum[t] = s;
  __syncthreads();
  if (t == 0) {
    int run = 0;
    for (int i = 0; i < 256; ++i) { int x = csum[i]; csum[i] = run; run += x; }
  }
  __syncthreads();
  int run = csum[t];
  for (int i = 0; i < chunk; ++i) {
    int idx = b + i;
    if (idx < nslot) { rowstart[idx] = run; run += deg[idx]; }
  }
}

__global__ __launch_bounds__(256) void k_efill(const int* __restrict__ esrc, const int* __restrict__ needed,
                                               const int* __restrict__ rowstart, const int* __restrict__ epos,
                                               int* __restrict__ elist, int NEdge) {
  int e = blockIdx.x * 256 + threadIdx.x;
  if (e >= NEdge) return;
  int p = epos[e];
  if (p >= 0) {
    int sl = needed[esrc[e]] - 1;
    elist[rowstart[sl] + p] = e;
  }
}

// ---------------- P GEMM: Pv = Ebf @ packedB ----------------
// M-tile 64, K=200. Staging = proven ugemm style: padded 116-u32 row stride, tail zeroed
// (kt=6 A-fragment reads bf16 cols up to 223 -> stride 232 covers it; pad is zero x B-zero).

#define P_LDA 116   // u32 per LDS A row (= 232 bf16; 200 data + zero pad)

__global__ __launch_bounds__(256) void k_pgemm(const u32* __restrict__ Ebf32,
                                               const unsigned short* __restrict__ Wbp,
                                               unsigned short* __restrict__ Pv, int NT) {
  __shared__ u32 Alds[64 * P_LDA];
  int tid = threadIdx.x, lane = tid & 63, wid = tid >> 6;
  size_t m0 = (size_t)blockIdx.x * 64;
  for (int u = tid; u < 64 * P_LDA; u += 256) {
    int r = u / P_LDA, c = u - r * P_LDA;
    u32 val = 0;
    if (c < 100) val = Ebf32[(m0 + r) * 100 + c];
    Alds[u] = val;
  }
  __syncthreads();
  const unsigned short* Abf = (const unsigned short*)Alds;
  int np = NT >> 1;
  for (int p = wid; p < np; p += 4) {
    f32x4 acc[2][4];
#pragma unroll
    for (int h = 0; h < 2; ++h)
#pragma unroll
      for (int rt = 0; rt < 4; ++rt) acc[h][rt] = (f32x4){0.f, 0.f, 0.f, 0.f};
#pragma unroll
    for (int kt = 0; kt < 7; ++kt) {
      s16x8 afr[4];
#pragma unroll
      for (int rt = 0; rt < 4; ++rt)
        afr[rt] = *(const s16x8*)(Abf + (rt * 16 + (lane & 15)) * (P_LDA * 2) + kt * 32 + ((lane >> 4) << 3));
#pragma unroll
      for (int h = 0; h < 2; ++h) {
        int nt = p * 2 + h;
        s16x8 bfr = *(const s16x8*)(Wbp + ((size_t)(kt * NT + nt)) * 512 + lane * 8);
#pragma unroll
        for (int rt = 0; rt < 4; ++rt)
          acc[h][rt] = __builtin_amdgcn_mfma_f32_16x16x32_bf16(afr[rt], bfr, acc[h][rt], 0, 0, 0);
      }
    }
#pragma unroll
    for (int h = 0; h < 2; ++h) {
      int colb = (p * 2 + h) * 16 + (lane & 15);
#pragma unroll
      for (int rt = 0; rt < 4; ++rt) {
#pragma unroll
        for (int r = 0; r < 4; ++r) {
          int row = rt * 16 + ((lane >> 4) << 2) + r;
          Pv[(m0 + row) * 800 + colb] = f2b(acc[rt == rt ? h : h][rt][r]);
        }
      }
    }
  }
}

// ---------------- V accumulation: V[h] = (Rv[he0]) + sum_{k} Pv[e_k, kblk] ----------------

__global__ __launch_bounds__(128) void k_vsum(const u32* __restrict__ Pv32, const float* __restrict__ Rv,
                                              const int* __restrict__ he, u32* __restrict__ V32, int kbase) {
  int h = blockIdx.x;
  int c = threadIdx.x;
  if (c >= 100) return;
  const int* hrow = he + (size_t)h * 7;
  float ax, ay;
  if (kbase == 0) {
    int r = hrow[0];
    ax = Rv[(size_t)r * 200 + 2 * c];
    ay = Rv[(size_t)r * 200 + 2 * c + 1];
  } else {
    u32 v = V32[(size_t)h * 100 + c];
    ax = b2f((unsigned short)v);
    ay = b2f((unsigned short)(v >> 16));
  }
#pragma unroll
  for (int k = 0; k < 3; ++k) {
    int e = hrow[1 + kbase + k];
    u32 g = Pv32[(size_t)e * 400 + k * 100 + c];
    ax += b2f((unsigned short)g);
    ay += b2f((unsigned short)(g >> 16));
  }
  V32[(size_t)h * 100 + c] = ((u32)f2b(ay) << 16) | (u32)f2b(ax);
}

// ---------------- gather-aggregate + bn/tanh -> outEc (compact, per slot) ----------------

__global__ __launch_bounds__(128) void k_gagg(const int* __restrict__ list, const int* __restrict__ cnt,
                                              const int* __restrict__ deg, const int* __restrict__ rowstart,
                                              const int* __restrict__ elist, const int* __restrict__ etyp,
                                              const int* __restrict__ edst,
                                              const u32* __restrict__ V32, const u32* __restrict__ Pv32,
                                              const float* __restrict__ E,
                                              const float* __restrict__ bnmp_g, const float* __restrict__ bnmp_b,
                                              float* __restrict__ outEc) {
  int slot = blockIdx.x;
  if (slot >= *cnt) return;
  int c = threadIdx.x;
  if (c >= 100) return;
  int n = list[slot];
  int nE = deg[slot];
  int rs = rowstart[slot];
  float ax = 0.f, ay = 0.f;
  for (int i = 0; i < nE; ++i) {
    int e = elist[rs + i];
    int et = etyp[e], dd = edst[e];
    u32 v = V32[(size_t)et * 100 + c];
    u32 g = Pv32[(size_t)dd * 400 + 300 + c];
    ax += b2f((unsigned short)v) + b2f((unsigned short)g);
    ay += b2f((unsigned short)(v >> 16)) + b2f((unsigned short)(g >> 16));
  }
  int j = 2 * c;
  float gx = bnmp_g[j] * BNS_F, bx = bnmp_b[j];
  float gy = bnmp_g[j + 1] * BNS_F, by = bnmp_b[j + 1];
  float ex = E[(size_t)n * 200 + j], ey = E[(size_t)n * 200 + j + 1];
  float ox = tanhf((0.5f * ax + 0.5f * ex) * gx + bx);
  float oy = tanhf((0.5f * ay + 0.5f * ey) * gy + by);
  *(float2*)(outEc + (size_t)slot * 200 + j) = make_float2(ox, oy);
}

// ---------------- build stk (B x 7 x 200), bn0 folded ----------------

__global__ __launch_bounds__(256) void k_stk(const float* __restrict__ outEc, const float* __restrict__ outR,
                                             const int* __restrict__ needed,
                                             const int* __restrict__ r_idx,
                                             const int* __restrict__ e1, const int* __restrict__ e2,
                                             const int* __restrict__ e3, const int* __restrict__ e4,
                                             const int* __restrict__ e5, const int* __restrict__ e6,
                                             const float* __restrict__ ms, int ent,
                                             const float* __restrict__ bn0_g, const float* __restrict__ bn0_b,
                                             float* __restrict__ stk) {
  int b = blockIdx.x; int j = threadIdx.x;
  if (j >= D) return;
  float s0 = bn0_g[0] * BNS_F, b0 = bn0_b[0];
  float* out = stk + (size_t)b * 1400;
  out[j] = outR[(size_t)r_idx[b] * D + j] * s0 + b0;
#pragma unroll
  for (int k = 0; k < 6; ++k) {
    const int* ep = (k == 0) ? e1 : (k == 1) ? e2 : (k == 2) ? e3 : (k == 3) ? e4 : (k == 4) ? e5 : e6;
    int slotq = needed[ent + k] - 1;
    int slote = needed[ep[b]] - 1;
    float q = outEc[(size_t)slotq * D + j];
    float v = outEc[(size_t)slote * D + j] * q * ms[(size_t)b * 6 + k];
    out[(1 + k) * D + j] = v * s0 + b0;
  }
}

// ---------------- conv + bn1 + relu -> x1 bf16 (half-batch, local rows, zero K-pad) ----------------

__global__ __launch_bounds__(256) void k_conv(const float* __restrict__ stk, const float* __restrict__ conv_w,
                                              const float* __restrict__ conv_b, const float* __restrict__ bn1_g,
                                              const float* __restrict__ bn1_b, unsigned short* __restrict__ x1,
                                              int KPAD, int b0) {
  __shared__ float srow[1400];
  __shared__ float cw[4200];
  __shared__ float cb[200], g1[200], b1[200];
  int b = blockIdx.x, tid = threadIdx.x;
  for (int u = tid; u < 1400; u += 256) srow[u] = stk[(size_t)(b0 + b) * 1400 + u];
  for (int u = tid; u < 4200; u += 256) cw[u] = conv_w[u];
  if (tid < 200) { cb[tid] = conv_b[tid]; g1[tid] = bn1_g[tid] * BNS_F; b1[tid] = bn1_b[tid]; }
  __syncthreads();
  for (int idx = tid; idx < FEAT; idx += 256) {
    int f = idx / 198, w = idx - f * 198;
    float acc = 0.f;
#pragma unroll
    for (int kh = 0; kh < 7; ++kh)
#pragma unroll
      for (int kw = 0; kw < 3; ++kw)
        acc += srow[kh * 200 + w + kw] * cw[f * 21 + kh * 3 + kw];
    float v = (acc + cb[f]) * g1[f] + b1[f];
    v = v > 0.f ? v : 0.f;
    x1[(size_t)b * KPAD + idx] = f2b(v);
  }
  for (int idx = FEAT + tid; idx < KPAD; idx += 256) x1[(size_t)b * KPAD + idx] = 0;
}

// ---------------- fc GEMM: M-tile 32, K-split, global_load_lds + XOR swizzle, partial slabs ----------------

__global__ __launch_bounds__(256) void k_fcgemm(const u32* __restrict__ X32,
                                                const unsigned short* __restrict__ Wpk,
                                                float* __restrict__ Ypart,
                                                int Mtot, int KU32, int KCH, int chPerSeg) {
  __shared__ u32 Alds[2][2048];
  int tid = threadIdx.x;
  int lane = tid & 63, wid = tid >> 6;
  int mblks = gridDim.x / FC_NSPLIT;
  int seg = blockIdx.x / mblks;
  int mblk = blockIdx.x - seg * mblks;
  int row0 = mblk * 32;
  int ch0 = seg * chPerSeg;
  int nCh = KCH - ch0; if (nCh > chPerSeg) nCh = chPerSeg;
  if (nCh <= 0) return;

  int nt0 = (wid == 0) ? 0 : (wid == 1) ? 4 : (wid == 2) ? 7 : 10;
  int ntc = (wid == 0) ? 4 : 3;

  f32x4 acc[2][4];
#pragma unroll
  for (int a = 0; a < 2; ++a)
#pragma unroll
    for (int b = 0; b < 4; ++b) acc[a][b] = (f32x4){0.f, 0.f, 0.f, 0.f};

  int srow0 = tid >> 4;
  int slch0 = (tid & 15) ^ (srow0 & 7);
  int srow1 = (tid + 256) >> 4;
  int slch1 = (tid & 15) ^ (srow1 & 7);
  int gr0 = row0 + srow0; if (gr0 >= Mtot) gr0 = Mtot - 1;
  int gr1 = row0 + srow1; if (gr1 >= Mtot) gr1 = Mtot - 1;
  const u32* src0 = X32 + (size_t)gr0 * KU32 + slch0 * 4;
  const u32* src1 = X32 + (size_t)gr1 * KU32 + slch1 * 4;

#define STAGE(bsel, ch)                                                        \
  do {                                                                         \
    gload_lds16(src0 + (size_t)(ch) * 64, &Alds[bsel][wid * 256]);             \
    gload_lds16(src1 + (size_t)(ch) * 64, &Alds[bsel][1024 + wid * 256]);      \
  } while (0)

  STAGE(0, ch0);
  __syncthreads();

  for (int i = 0; i < nCh; ++i) {
    if (i + 1 < nCh) STAGE((i + 1) & 1, ch0 + i + 1);
    const unsigned short* buf = (const unsigned short*)Alds[i & 1];
    int ch = ch0 + i;
#pragma unroll
    for (int kkt = 0; kkt < 4; ++kkt) {
      s16x8 afr[2];
#pragma unroll
      for (int rt = 0; rt < 2; ++rt) {
        int row = rt * 16 + (lane & 15);
        int pch = ((kkt << 2) + (lane >> 4)) ^ (row & 7);
        afr[rt] = *(const s16x8*)(buf + row * 128 + pch * 8);
      }
      size_t ktg = (size_t)(ch * 4 + kkt);
#pragma unroll
      for (int ln = 0; ln < 4; ++ln) {
        if (ln < ntc) {
          s16x8 bfr = *(const s16x8*)(Wpk + (ktg * 13 + nt0 + ln) * 512 + lane * 8);
          acc[0][ln] = __builtin_amdgcn_mfma_f32_16x16x32_bf16(afr[0], bfr, acc[0][ln], 0, 0, 0);
          acc[1][ln] = __builtin_amdgcn_mfma_f32_16x16x32_bf16(afr[1], bfr, acc[1][ln], 0, 0, 0);
        }
      }
    }
    __syncthreads();
  }
#undef STAGE

  float* Yp = Ypart + (size_t)seg * Mtot * 208;
#pragma unroll
  for (int rt = 0; rt < 2; ++rt) {
#pragma unroll
    for (int ln = 0; ln < 4; ++ln) {
      if (ln < ntc) {
        int j = (nt0 + ln) * 16 + (lane & 15);
#pragma unroll
        for (int r = 0; r < 4; ++r) {
          int b = row0 + rt * 16 + ((lane >> 4) << 2) + r;
          if (b < Mtot) Yp[(size_t)b * 208 + j] = acc[rt][ln][r];
        }
      }
    }
  }
}

// ---------------- reduce partials + fc_b + bn2 + relu + row-sum -> out ----------------

__global__ __launch_bounds__(256) void k_epilogue(const float* __restrict__ Ypart, const float* __restrict__ fc_b,
                                                  const float* __restrict__ bn2_g, const float* __restrict__ bn2_b,
                                                  float* __restrict__ out, int Mtot, int b0) {
  __shared__ float red[4];
  int b = blockIdx.x, tid = threadIdx.x;
  float v = 0.f;
  if (tid < D) {
    float y = fc_b[tid];
#pragma unroll
    for (int s = 0; s < FC_NSPLIT; ++s) y += Ypart[((size_t)s * Mtot + b) * 208 + tid];
    y = y * (bn2_g[tid] * BNS_F) + bn2_b[tid];
    v = y > 0.f ? y : 0.f;
  }
#pragma unroll
  for (int o = 32; o > 0; o >>= 1) v += __shfl_down(v, o);
  if ((tid & 63) == 0) red[tid >> 6] = v;
  __syncthreads();
  if (tid == 0) out[b0 + b] = red[0] + red[1] + red[2] + red[3];
}

// ---------------- host launch ----------------

extern "C" void kernel_launch(void* const* d_in, const int* in_sizes, int n_in,
                              void* d_out, int out_size, void* d_ws, size_t ws_size,
                              hipStream_t stream) {
  const float* E          = (const float*)d_in[0];
  const float* R          = (const float*)d_in[1];
  const float* w_alle     = (const float*)d_in[2];
  const float* w_addpos   = (const float*)d_in[3];
  const float* w_alleandr = (const float*)d_in[4];
  const float* w_rel      = (const float*)d_in[5];
  const float* conv_w     = (const float*)d_in[6];
  const float* conv_b     = (const float*)d_in[7];
  const float* fc_w       = (const float*)d_in[8];
  const float* fc_b       = (const float*)d_in[9];
  const float* bnmp_g     = (const float*)d_in[10];
  const float* bnmp_b     = (const float*)d_in[11];
  const float* bn0_g      = (const float*)d_in[12];
  const float* bn0_b      = (const float*)d_in[13];
  const float* bn1_g      = (const float*)d_in[14];
  const float* bn1_b      = (const float*)d_in[15];
  const float* bn2_g      = (const float*)d_in[16];
  const float* bn2_b      = (const float*)d_in[17];
  const float* ms         = (const float*)d_in[18];
  const int* hyperedge    = (const int*)d_in[19];
  const int* edge_index   = (const int*)d_in[20];
  const int* edge_type    = (const int*)d_in[21];
  const int* r_idx        = (const int*)d_in[22];
  const int* e1 = (const int*)d_in[23];
  const int* e2 = (const int*)d_in[24];
  const int* e3 = (const int*)d_in[25];
  const int* e4 = (const int*)d_in[26];
  const int* e5 = (const int*)d_in[27];
  const int* e6 = (const int*)d_in[28];

  const int Nn    = in_sizes[0] / D;        // 50006
  const int NR    = in_sizes[1] / D;        // 2000
  const int Hh    = in_sizes[19] / 7;       // 100000
  const int NEdge = in_sizes[21];           // 600000
  const int B     = in_sizes[22];           // 2048
  const int ent   = Nn - 6;                 // == ent_num by construction
  const int K_fc  = in_sizes[8] / D;        // 39600
  const int KCH   = (K_fc + 127) / 128;     // 310
  const int KPAD  = KCH * 128;              // 39680
  const int KU32  = KPAD / 2;               // 19840
  const int chPerSeg = (KCH + FC_NSPLIT - 1) / FC_NSPLIT;  // 20
  const int KT_tot = KCH * 4;               // 1240
  const int NSLOT = 6 * B + 6;              // 12294
  const int MPAD  = ((Nn + 63) / 64) * 64;  // 50048
  const int NT_A = 38, NT_B = 50;

  const int* esrc = edge_index;
  const int* edst = edge_index + NEdge;

  char* W = (char*)d_ws;
  size_t off = 0;
  auto alloc = [&](size_t bytes) { size_t o = off; off += (bytes + 255) & ~(size_t)255; return o; };
  // persistent
  size_t o_Wfc  = alloc((size_t)KT_tot * 13 * 512 * 2);
  size_t o_WbpA = alloc((size_t)7 * NT_A * 512 * 2);
  size_t o_WbpB = alloc((size_t)7 * NT_B * 512 * 2);
  size_t o_Wtop = alloc((size_t)200 * 200 * 4);
  size_t o_T    = alloc((size_t)1200 * 200 * 4);
  size_t o_Rv   = alloc((size_t)NR * 200 * 4);
  size_t o_outR = alloc((size_t)NR * 200 * 4);
  size_t o_need = alloc(((size_t)Nn + 1) * 4);  // + cnt at [Nn]
  size_t o_list = alloc((size_t)NSLOT * 4 + 64);
  size_t o_deg  = alloc((size_t)NSLOT * 4 + 64);
  size_t o_rs   = alloc((size_t)NSLOT * 4 + 64);
  size_t o_epos = alloc((size_t)NEdge * 4);
  size_t o_elist= alloc((size_t)NEdge * 4);
  size_t o_outEc= alloc((size_t)NSLOT * 200 * 4);
  size_t o_stk  = alloc((size_t)B * 1400 * 4);
  // region A (phase-1: Pv|V|Ebf ; phase-2: x1|Ypart)
  size_t o_A    = off;
  size_t o_Pv   = alloc((size_t)MPAD * 800 * 2);
  size_t o_V    = alloc((size_t)Hh * 200 * 2);
  size_t o_Ebf  = alloc((size_t)MPAD * 200 * 2);
  size_t regionA_end = off;

  size_t x1_bytes = (size_t)BHALF * KPAD * 2;
  size_t o_x1 = o_A;
  size_t o_Yp = o_A + ((x1_bytes + 255) & ~(size_t)255);
  size_t yp_bytes = (size_t)FC_NSPLIT * BHALF * 208 * 4;
  if (ws_size < off) return;
  if (o_Yp + yp_bytes > regionA_end) return;

  unsigned short* Wfc  = (unsigned short*)(W + o_Wfc);
  unsigned short* WbpA = (unsigned short*)(W + o_WbpA);
  unsigned short* WbpB = (unsigned short*)(W + o_WbpB);
  float* Wtop  = (float*)(W + o_Wtop);
  float* T     = (float*)(W + o_T);
  float* Rv    = (float*)(W + o_Rv);
  float* outR  = (float*)(W + o_outR);
  int*   needed= (int*)(W + o_need);
  int*   cnt   = needed + Nn;
  int*   list  = (int*)(W + o_list);
  int*   deg   = (int*)(W + o_deg);
  int*   rs    = (int*)(W + o_rs);
  int*   epos  = (int*)(W + o_epos);
  int*   elist = (int*)(W + o_elist);
  float* outEc = (float*)(W + o_outEc);
  float* stk   = (float*)(W + o_stk);
  unsigned short* Pv  = (unsigned short*)(W + o_Pv);
  unsigned short* Vb  = (unsigned short*)(W + o_V);
  unsigned short* Ebf = (unsigned short*)(W + o_Ebf);
  unsigned short* x1  = (unsigned short*)(W + o_x1);
  float* Ypart        = (float*)(W + o_Yp);

  hipMemsetAsync(needed, 0, ((size_t)Nn + 1) * 4, stream);
  hipMemsetAsync(deg, 0, (size_t)NSLOT * 4, stream);

  // prep chain
  hipLaunchKernelGGL(k_cvt_bf16, dim3(4096), dim3(256), 0, stream, E, Ebf, Nn * D);
  hipLaunchKernelGGL(k_sgemm, dim3(25), dim3(256), 0, stream, w_alleandr, w_addpos, Wtop, 200, (const float*)nullptr, 1.0f);
  hipLaunchKernelGGL(k_sgemm, dim3(150), dim3(256), 0, stream, w_alle, Wtop, T, 1200, E + (size_t)ent * D, 0.5f);
  hipLaunchKernelGGL(k_sgemm, dim3(250), dim3(256), 0, stream, R, Wtop, Rv, NR, (const float*)nullptr, 0.5f);
  hipLaunchKernelGGL(k_sgemm, dim3(250), dim3(256), 0, stream, R, w_rel, outR, NR, (const float*)nullptr, 1.0f);
  hipLaunchKernelGGL(k_packB, dim3(7 * NT_A), dim3(64), 0, stream, T, w_addpos, WbpA, NT_A, 0, 0);
  hipLaunchKernelGGL(k_packB, dim3(7 * NT_B), dim3(64), 0, stream, T, w_addpos, WbpB, NT_B, 3, 1);
  hipLaunchKernelGGL(k_prep_wfc, dim3(KT_tot * 13), dim3(64), 0, stream, fc_w, Wfc, K_fc);

  // mask / compact / CSR
  hipLaunchKernelGGL(k_mask, dim3((6 * B + 6 + 255) / 256), dim3(256), 0, stream,
                     e1, e2, e3, e4, e5, e6, ent, needed, B);
  hipLaunchKernelGGL(k_compact, dim3((Nn + 255) / 256), dim3(256), 0, stream, needed, list, cnt, Nn);
  hipLaunchKernelGGL(k_ecount, dim3((NEdge + 255) / 256), dim3(256), 0, stream, esrc, needed, deg, epos, NEdge);
  hipLaunchKernelGGL(k_prefix, dim3(1), dim3(256), 0, stream, deg, rs, NSLOT);
  hipLaunchKernelGGL(k_efill, dim3((NEdge + 255) / 256), dim3(256), 0, stream, esrc, needed, rs, epos, elist, NEdge);

  // P / V pipeline (two N-passes sharing Pv buffer)
  hipLaunchKernelGGL(k_pgemm, dim3(MPAD / 64), dim3(256), 0, stream, (const u32*)Ebf, WbpA, Pv, NT_A);
  hipLaunchKernelGGL(k_vsum, dim3(Hh), dim3(128), 0, stream, (const u32*)Pv, Rv, hyperedge, (u32*)Vb, 0);
  hipLaunchKernelGGL(k_pgemm, dim3(MPAD / 64), dim3(256), 0, stream, (const u32*)Ebf, WbpB, Pv, NT_B);
  hipLaunchKernelGGL(k_vsum, dim3(Hh), dim3(128), 0, stream, (const u32*)Pv, Rv, hyperedge, (u32*)Vb, 3);

  // aggregate + outE (compact)
  hipLaunchKernelGGL(k_gagg, dim3(NSLOT), dim3(128), 0, stream,
                     list, cnt, deg, rs, elist, edge_type, edst,
                     (const u32*)Vb, (const u32*)Pv, E, bnmp_g, bnmp_b, outEc);

  // stk
  hipLaunchKernelGGL(k_stk, dim3(B), dim3(256), 0, stream,
                     outEc, outR, needed, r_idx, e1, e2, e3, e4, e5, e6, ms, ent, bn0_g, bn0_b, stk);

  // conv + fc + epilogue in two half-batches (x1/Ypart alias phase-1 buffers)
  for (int half = 0; half < 2; ++half) {
    int b0 = half * BHALF;
    hipLaunchKernelGGL(k_conv, dim3(BHALF), dim3(256), 0, stream, stk, conv_w, conv_b, bn1_g, bn1_b, x1, KPAD, b0);
    hipLaunchKernelGGL(k_fcgemm, dim3((BHALF / 32) * FC_NSPLIT), dim3(256), 0, stream,
                       (const u32*)x1, Wfc, Ypart, BHALF, KU32, KCH, chPerSeg);
    hipLaunchKernelGGL(k_epilogue, dim3(BHALF), dim3(256), 0, stream, Ypart, fc_b, bn2_g, bn2_b, (float*)d_out, BHALF, b0);
  }
}

// Round 6
// 896.894 us; speedup vs baseline: 1.6729x; 1.0903x over previous
//
#include <hip/hip_runtime.h>

#define D 200
#define FEAT 39600
#define BNS_F 0.9999950000374997f   // 1/sqrt(1+1e-5)
#define FC_NSPLIT 16
#define BHALF 1024

typedef float f32x4 __attribute__((ext_vector_type(4)));
typedef short s16x8 __attribute__((ext_vector_type(8)));
typedef unsigned int u32;

static __device__ __forceinline__ unsigned short f2b(float f) {
  union { float f; unsigned u; } v; v.f = f;
  return (unsigned short)((v.u + 0x7FFFu + ((v.u >> 16) & 1u)) >> 16);
}
static __device__ __forceinline__ float b2f(unsigned short h) {
  union { unsigned u; float f; } v; v.u = ((unsigned)h) << 16;
  return v.f;
}
static __device__ __forceinline__ void gload_lds16(const void* g, void* l) {
  __builtin_amdgcn_global_load_lds((const __attribute__((address_space(1))) u32*)g,
                                   (__attribute__((address_space(3))) u32*)l, 16, 0, 0);
}

// ---------------- prep ----------------

__global__ __launch_bounds__(256) void k_cvt_bf16(const float* __restrict__ src,
                                                  unsigned short* __restrict__ dst, int n) {
  int stride = gridDim.x * 256;
  for (int i = blockIdx.x * 256 + threadIdx.x; i < n; i += stride) dst[i] = f2b(src[i]);
}

// generic small GEMM: C[r][j] = scale * rowscale[r] * sum_u A[r][u] * Bm[u][j]   (K=N=200)
__global__ __launch_bounds__(256) void k_sgemm(const float* __restrict__ A, const float* __restrict__ Bm,
                                               float* __restrict__ C, int M,
                                               const float* __restrict__ rowscale, float scale) {
  __shared__ float A8[8][200];
  int tid = threadIdx.x;
  int m0 = blockIdx.x * 8;
  for (int u = tid; u < 8 * 200; u += 256) {
    int m = u / 200, k = u - m * 200;
    A8[m][k] = (m0 + m < M) ? A[(size_t)(m0 + m) * 200 + k] : 0.f;
  }
  __syncthreads();
  int j = tid; if (j >= 200) return;
  float acc[8] = {0,0,0,0,0,0,0,0};
  for (int u = 0; u < 200; ++u) {
    float b = Bm[u * 200 + j];
#pragma unroll
    for (int m = 0; m < 8; ++m) acc[m] += A8[m][u] * b;
  }
#pragma unroll
  for (int m = 0; m < 8; ++m) {
    int r = m0 + m;
    if (r < M) {
      float s = scale * (rowscale ? rowscale[r] : 1.f);
      C[(size_t)r * 200 + j] = acc[m] * s;
    }
  }
}

// pack B fragments for P-GEMM. cols<600: T[kofs + col/200][kk][col%200]; 600..799 (if useG): w_addpos[200+kk][col-600]
__global__ __launch_bounds__(64) void k_packB(const float* __restrict__ T, const float* __restrict__ w_addpos,
                                              unsigned short* __restrict__ out, int NT, int kofs, int useG) {
  int blk = blockIdx.x;          // kt*NT + nt
  int lane = threadIdx.x;
  int nt = blk % NT, kt = blk / NT;
  int col = nt * 16 + (lane & 15);
  unsigned short* p = out + (size_t)blk * 512 + lane * 8;
#pragma unroll
  for (int t = 0; t < 8; ++t) {
    int kk = kt * 32 + ((lane >> 4) << 3) + t;
    float v = 0.f;
    if (kk < 200) {
      if (col < 600) {
        int k = col / 200;
        v = T[(size_t)((kofs + k) * 200 + kk) * 200 + (col - k * 200)];
      } else if (useG && col < 800) {
        v = w_addpos[(size_t)(200 + kk) * 200 + (col - 600)];
      }
    }
    p[t] = f2b(v);
  }
}

// fc_w -> packed bf16 fragments [kt][nt(13)][512], K' permuted to w-major: K' = w*200 + f
// (matches k_conv's x1 layout; original fc row = f*198 + w)
__global__ __launch_bounds__(64) void k_prep_wfc(const float* __restrict__ fc_w,
                                                 unsigned short* __restrict__ Wpk, int K) {
  int blk = blockIdx.x;   // kt*13 + nt
  int lane = threadIdx.x;
  int nt = blk % 13; int kt = blk / 13;
  int j = nt * 16 + (lane & 15);
  unsigned short* p = Wpk + (size_t)blk * 512 + lane * 8;
#pragma unroll
  for (int t = 0; t < 8; ++t) {
    int kk = kt * 32 + ((lane >> 4) << 3) + t;   // K' index
    int w = kk / 200, f = kk - w * 200;
    float v = (w < 198 && j < D) ? fc_w[(size_t)(f * 198 + w) * D + j] : 0.f;
    p[t] = f2b(v);
  }
}

// ---------------- needed mask / compaction / CSR ----------------

__global__ __launch_bounds__(256) void k_mask(const int* __restrict__ e1, const int* __restrict__ e2,
                                              const int* __restrict__ e3, const int* __restrict__ e4,
                                              const int* __restrict__ e5, const int* __restrict__ e6,
                                              int ent, int* __restrict__ needed, int B) {
  int t = blockIdx.x * 256 + threadIdx.x;
  int total = 6 * B;
  if (t < total) {
    int k = t / B, b = t - k * B;
    const int* p = (k == 0) ? e1 : (k == 1) ? e2 : (k == 2) ? e3 : (k == 3) ? e4 : (k == 4) ? e5 : e6;
    needed[p[b]] = 1;
  } else if (t < total + 6) {
    needed[ent + (t - total)] = 1;
  }
}

__global__ __launch_bounds__(256) void k_compact(int* __restrict__ needed,
                                                 int* __restrict__ list, int* __restrict__ cnt, int Nn) {
  int n = blockIdx.x * 256 + threadIdx.x;
  if (n < Nn && needed[n]) {
    int p = atomicAdd(cnt, 1);
    list[p] = n;
    needed[n] = p + 1;
  }
}

__global__ __launch_bounds__(256) void k_ecount(const int* __restrict__ esrc, const int* __restrict__ needed,
                                                int* __restrict__ deg, int* __restrict__ epos, int NEdge) {
  int e = blockIdx.x * 256 + threadIdx.x;
  if (e >= NEdge) return;
  int sl = needed[esrc[e]];
  epos[e] = (sl > 0) ? atomicAdd(&deg[sl - 1], 1) : -1;
}

__global__ __launch_bounds__(256) void k_prefix(const int* __restrict__ deg, int* __restrict__ rowstart, int nslot) {
  __shared__ int csum[256];
  int t = threadIdx.x;
  int chunk = (nslot + 255) / 256;
  int b = t * chunk;
  int s = 0;
  for (int i = 0; i < chunk; ++i) { int idx = b + i; if (idx < nslot) s += deg[idx]; }
  csum[t] = s;
  __syncthreads();
  if (t == 0) {
    int run = 0;
    for (int i = 0; i < 256; ++i) { int x = csum[i]; csum[i] = run; run += x; }
  }
  __syncthreads();
  int run = csum[t];
  for (int i = 0; i < chunk; ++i) {
    int idx = b + i;
    if (idx < nslot) { rowstart[idx] = run; run += deg[idx]; }
  }
}

__global__ __launch_bounds__(256) void k_efill(const int* __restrict__ esrc, const int* __restrict__ needed,
                                               const int* __restrict__ rowstart, const int* __restrict__ epos,
                                               int* __restrict__ elist, int NEdge) {
  int e = blockIdx.x * 256 + threadIdx.x;
  if (e >= NEdge) return;
  int p = epos[e];
  if (p >= 0) {
    int sl = needed[esrc[e]] - 1;
    elist[rowstart[sl] + p] = e;
  }
}

// ---------------- P GEMM: Pv = Ebf @ packedB ----------------

#define P_LDA 116   // u32 per LDS A row (= 232 bf16; 200 data + zero pad)

__global__ __launch_bounds__(256) void k_pgemm(const u32* __restrict__ Ebf32,
                                               const unsigned short* __restrict__ Wbp,
                                               unsigned short* __restrict__ Pv, int NT) {
  __shared__ u32 Alds[64 * P_LDA];
  int tid = threadIdx.x, lane = tid & 63, wid = tid >> 6;
  size_t m0 = (size_t)blockIdx.x * 64;
  for (int u = tid; u < 64 * P_LDA; u += 256) {
    int r = u / P_LDA, c = u - r * P_LDA;
    u32 val = 0;
    if (c < 100) val = Ebf32[(m0 + r) * 100 + c];
    Alds[u] = val;
  }
  __syncthreads();
  const unsigned short* Abf = (const unsigned short*)Alds;
  int np = NT >> 1;
  for (int p = wid; p < np; p += 4) {
    f32x4 acc[2][4];
#pragma unroll
    for (int h = 0; h < 2; ++h)
#pragma unroll
      for (int rt = 0; rt < 4; ++rt) acc[h][rt] = (f32x4){0.f, 0.f, 0.f, 0.f};
#pragma unroll
    for (int kt = 0; kt < 7; ++kt) {
      s16x8 afr[4];
#pragma unroll
      for (int rt = 0; rt < 4; ++rt)
        afr[rt] = *(const s16x8*)(Abf + (rt * 16 + (lane & 15)) * (P_LDA * 2) + kt * 32 + ((lane >> 4) << 3));
#pragma unroll
      for (int h = 0; h < 2; ++h) {
        int nt = p * 2 + h;
        s16x8 bfr = *(const s16x8*)(Wbp + ((size_t)(kt * NT + nt)) * 512 + lane * 8);
#pragma unroll
        for (int rt = 0; rt < 4; ++rt)
          acc[h][rt] = __builtin_amdgcn_mfma_f32_16x16x32_bf16(afr[rt], bfr, acc[h][rt], 0, 0, 0);
      }
    }
#pragma unroll
    for (int h = 0; h < 2; ++h) {
      int colb = (p * 2 + h) * 16 + (lane & 15);
#pragma unroll
      for (int rt = 0; rt < 4; ++rt) {
#pragma unroll
        for (int r = 0; r < 4; ++r) {
          int row = rt * 16 + ((lane >> 4) << 2) + r;
          Pv[(m0 + row) * 800 + colb] = f2b(acc[h][rt][r]);
        }
      }
    }
  }
}

// ---------------- V accumulation: V[h] = (Rv[he0]) + sum_{k} Pv[e_k, kblk] ----------------

__global__ __launch_bounds__(128) void k_vsum(const u32* __restrict__ Pv32, const float* __restrict__ Rv,
                                              const int* __restrict__ he, u32* __restrict__ V32, int kbase) {
  int h = blockIdx.x;
  int c = threadIdx.x;
  if (c >= 100) return;
  const int* hrow = he + (size_t)h * 7;
  float ax, ay;
  if (kbase == 0) {
    int r = hrow[0];
    ax = Rv[(size_t)r * 200 + 2 * c];
    ay = Rv[(size_t)r * 200 + 2 * c + 1];
  } else {
    u32 v = V32[(size_t)h * 100 + c];
    ax = b2f((unsigned short)v);
    ay = b2f((unsigned short)(v >> 16));
  }
#pragma unroll
  for (int k = 0; k < 3; ++k) {
    int e = hrow[1 + kbase + k];
    u32 g = Pv32[(size_t)e * 400 + k * 100 + c];
    ax += b2f((unsigned short)g);
    ay += b2f((unsigned short)(g >> 16));
  }
  V32[(size_t)h * 100 + c] = ((u32)f2b(ay) << 16) | (u32)f2b(ax);
}

// ---------------- gather-aggregate + bn/tanh -> outEc (compact, per slot) ----------------

__global__ __launch_bounds__(128) void k_gagg(const int* __restrict__ list, const int* __restrict__ cnt,
                                              const int* __restrict__ deg, const int* __restrict__ rowstart,
                                              const int* __restrict__ elist, const int* __restrict__ etyp,
                                              const int* __restrict__ edst,
                                              const u32* __restrict__ V32, const u32* __restrict__ Pv32,
                                              const float* __restrict__ E,
                                              const float* __restrict__ bnmp_g, const float* __restrict__ bnmp_b,
                                              float* __restrict__ outEc) {
  int slot = blockIdx.x;
  if (slot >= *cnt) return;
  int c = threadIdx.x;
  if (c >= 100) return;
  int n = list[slot];
  int nE = deg[slot];
  int rs = rowstart[slot];
  float ax = 0.f, ay = 0.f;
  for (int i = 0; i < nE; ++i) {
    int e = elist[rs + i];
    int et = etyp[e], dd = edst[e];
    u32 v = V32[(size_t)et * 100 + c];
    u32 g = Pv32[(size_t)dd * 400 + 300 + c];
    ax += b2f((unsigned short)v) + b2f((unsigned short)g);
    ay += b2f((unsigned short)(v >> 16)) + b2f((unsigned short)(g >> 16));
  }
  int j = 2 * c;
  float gx = bnmp_g[j] * BNS_F, bx = bnmp_b[j];
  float gy = bnmp_g[j + 1] * BNS_F, by = bnmp_b[j + 1];
  float ex = E[(size_t)n * 200 + j], ey = E[(size_t)n * 200 + j + 1];
  float ox = tanhf((0.5f * ax + 0.5f * ex) * gx + bx);
  float oy = tanhf((0.5f * ay + 0.5f * ey) * gy + by);
  *(float2*)(outEc + (size_t)slot * 200 + j) = make_float2(ox, oy);
}

// ---------------- build stk (B x 7 x 200), bn0 folded ----------------

__global__ __launch_bounds__(256) void k_stk(const float* __restrict__ outEc, const float* __restrict__ outR,
                                             const int* __restrict__ needed,
                                             const int* __restrict__ r_idx,
                                             const int* __restrict__ e1, const int* __restrict__ e2,
                                             const int* __restrict__ e3, const int* __restrict__ e4,
                                             const int* __restrict__ e5, const int* __restrict__ e6,
                                             const float* __restrict__ ms, int ent,
                                             const float* __restrict__ bn0_g, const float* __restrict__ bn0_b,
                                             float* __restrict__ stk) {
  int b = blockIdx.x; int j = threadIdx.x;
  if (j >= D) return;
  float s0 = bn0_g[0] * BNS_F, b0 = bn0_b[0];
  float* out = stk + (size_t)b * 1400;
  out[j] = outR[(size_t)r_idx[b] * D + j] * s0 + b0;
#pragma unroll
  for (int k = 0; k < 6; ++k) {
    const int* ep = (k == 0) ? e1 : (k == 1) ? e2 : (k == 2) ? e3 : (k == 3) ? e4 : (k == 4) ? e5 : e6;
    int slotq = needed[ent + k] - 1;
    int slote = needed[ep[b]] - 1;
    float q = outEc[(size_t)slotq * D + j];
    float v = outEc[(size_t)slote * D + j] * q * ms[(size_t)b * 6 + k];
    out[(1 + k) * D + j] = v * s0 + b0;
  }
}

// ---------------- conv + bn1 + relu -> x1 bf16, K' = w*200 + f (w-major) ----------------
// wave-per-strip register blocking: srow window broadcast into regs, lane = filter f.

__global__ __launch_bounds__(256) void k_conv(const float* __restrict__ stk, const float* __restrict__ conv_w,
                                              const float* __restrict__ conv_b, const float* __restrict__ bn1_g,
                                              const float* __restrict__ bn1_b, unsigned short* __restrict__ x1,
                                              int KPAD, int b0) {
  __shared__ float srow[1408];
  __shared__ float cw[4200];
  __shared__ float cb[200], g1[200], b1[200];
  int b = blockIdx.x, tid = threadIdx.x;
  for (int u = tid; u < 1400; u += 256) srow[u] = stk[(size_t)(b0 + b) * 1400 + u];
  if (tid < 8) srow[1400 + tid] = 0.f;
  for (int u = tid; u < 4200; u += 256) cw[u] = conv_w[u];
  if (tid < 200) { cb[tid] = conv_b[tid]; g1[tid] = bn1_g[tid] * BNS_F; b1[tid] = bn1_b[tid]; }
  __syncthreads();
  int lane = tid & 63, wid = tid >> 6;
  unsigned short* xrow = x1 + (size_t)b * KPAD;
  for (int strip = wid; strip < 25; strip += 4) {
    int w0 = strip * 8;
    int nw = 198 - w0; if (nw > 8) nw = 8;
    float sreg[7][10];
#pragma unroll
    for (int kh = 0; kh < 7; ++kh)
#pragma unroll
      for (int i = 0; i < 10; ++i)
        sreg[kh][i] = srow[kh * 200 + w0 + i];
#pragma unroll
    for (int q = 0; q < 4; ++q) {
      int f = lane + q * 64;
      if (f < 200) {
        float acc[8];
#pragma unroll
        for (int i = 0; i < 8; ++i) acc[i] = 0.f;
#pragma unroll
        for (int kh = 0; kh < 7; ++kh) {
          float c0 = cw[f * 21 + kh * 3 + 0];
          float c1 = cw[f * 21 + kh * 3 + 1];
          float c2 = cw[f * 21 + kh * 3 + 2];
#pragma unroll
          for (int i = 0; i < 8; ++i)
            acc[i] += sreg[kh][i] * c0 + sreg[kh][i + 1] * c1 + sreg[kh][i + 2] * c2;
        }
        float gf = g1[f], bf = b1[f], cf = cb[f];
#pragma unroll
        for (int i = 0; i < 8; ++i) {
          if (i < nw) {
            float v = (acc[i] + cf) * gf + bf;
            v = v > 0.f ? v : 0.f;
            xrow[(size_t)(w0 + i) * 200 + f] = f2b(v);
          }
        }
      }
    }
  }
  for (int idx = FEAT + tid; idx < KPAD; idx += 256) xrow[idx] = 0;
}

// ---------------- fc GEMM: M-tile 32, K-split, global_load_lds + XOR swizzle, partial slabs ----------------

__global__ __launch_bounds__(256) void k_fcgemm(const u32* __restrict__ X32,
                                                const unsigned short* __restrict__ Wpk,
                                                float* __restrict__ Ypart,
                                                int Mtot, int KU32, int KCH, int chPerSeg) {
  __shared__ u32 Alds[2][2048];
  int tid = threadIdx.x;
  int lane = tid & 63, wid = tid >> 6;
  int mblks = gridDim.x / FC_NSPLIT;
  int seg = blockIdx.x / mblks;
  int mblk = blockIdx.x - seg * mblks;
  int row0 = mblk * 32;
  int ch0 = seg * chPerSeg;
  int nCh = KCH - ch0; if (nCh > chPerSeg) nCh = chPerSeg;
  if (nCh <= 0) return;

  int nt0 = (wid == 0) ? 0 : (wid == 1) ? 4 : (wid == 2) ? 7 : 10;
  int ntc = (wid == 0) ? 4 : 3;

  f32x4 acc[2][4];
#pragma unroll
  for (int a = 0; a < 2; ++a)
#pragma unroll
    for (int b = 0; b < 4; ++b) acc[a][b] = (f32x4){0.f, 0.f, 0.f, 0.f};

  int srow0 = tid >> 4;
  int slch0 = (tid & 15) ^ (srow0 & 7);
  int srow1 = (tid + 256) >> 4;
  int slch1 = (tid & 15) ^ (srow1 & 7);
  int gr0 = row0 + srow0; if (gr0 >= Mtot) gr0 = Mtot - 1;
  int gr1 = row0 + srow1; if (gr1 >= Mtot) gr1 = Mtot - 1;
  const u32* src0 = X32 + (size_t)gr0 * KU32 + slch0 * 4;
  const u32* src1 = X32 + (size_t)gr1 * KU32 + slch1 * 4;

#define STAGE(bsel, ch)                                                        \
  do {                                                                         \
    gload_lds16(src0 + (size_t)(ch) * 64, &Alds[bsel][wid * 256]);             \
    gload_lds16(src1 + (size_t)(ch) * 64, &Alds[bsel][1024 + wid * 256]);      \
  } while (0)

  STAGE(0, ch0);
  __syncthreads();

  for (int i = 0; i < nCh; ++i) {
    if (i + 1 < nCh) STAGE((i + 1) & 1, ch0 + i + 1);
    const unsigned short* buf = (const unsigned short*)Alds[i & 1];
    int ch = ch0 + i;
#pragma unroll
    for (int kkt = 0; kkt < 4; ++kkt) {
      s16x8 afr[2];
#pragma unroll
      for (int rt = 0; rt < 2; ++rt) {
        int row = rt * 16 + (lane & 15);
        int pch = ((kkt << 2) + (lane >> 4)) ^ (row & 7);
        afr[rt] = *(const s16x8*)(buf + row * 128 + pch * 8);
      }
      size_t ktg = (size_t)(ch * 4 + kkt);
#pragma unroll
      for (int ln = 0; ln < 4; ++ln) {
        if (ln < ntc) {
          s16x8 bfr = *(const s16x8*)(Wpk + (ktg * 13 + nt0 + ln) * 512 + lane * 8);
          acc[0][ln] = __builtin_amdgcn_mfma_f32_16x16x32_bf16(afr[0], bfr, acc[0][ln], 0, 0, 0);
          acc[1][ln] = __builtin_amdgcn_mfma_f32_16x16x32_bf16(afr[1], bfr, acc[1][ln], 0, 0, 0);
        }
      }
    }
    __syncthreads();
  }
#undef STAGE

  float* Yp = Ypart + (size_t)seg * Mtot * 208;
#pragma unroll
  for (int rt = 0; rt < 2; ++rt) {
#pragma unroll
    for (int ln = 0; ln < 4; ++ln) {
      if (ln < ntc) {
        int j = (nt0 + ln) * 16 + (lane & 15);
#pragma unroll
        for (int r = 0; r < 4; ++r) {
          int b = row0 + rt * 16 + ((lane >> 4) << 2) + r;
          if (b < Mtot) Yp[(size_t)b * 208 + j] = acc[rt][ln][r];
        }
      }
    }
  }
}

// ---------------- reduce partials + fc_b + bn2 + relu + row-sum -> out ----------------

__global__ __launch_bounds__(256) void k_epilogue(const float* __restrict__ Ypart, const float* __restrict__ fc_b,
                                                  const float* __restrict__ bn2_g, const float* __restrict__ bn2_b,
                                                  float* __restrict__ out, int Mtot, int b0) {
  __shared__ float red[4];
  int b = blockIdx.x, tid = threadIdx.x;
  float v = 0.f;
  if (tid < D) {
    float y = fc_b[tid];
#pragma unroll
    for (int s = 0; s < FC_NSPLIT; ++s) y += Ypart[((size_t)s * Mtot + b) * 208 + tid];
    y = y * (bn2_g[tid] * BNS_F) + bn2_b[tid];
    v = y > 0.f ? y : 0.f;
  }
#pragma unroll
  for (int o = 32; o > 0; o >>= 1) v += __shfl_down(v, o);
  if ((tid & 63) == 0) red[tid >> 6] = v;
  __syncthreads();
  if (tid == 0) out[b0 + b] = red[0] + red[1] + red[2] + red[3];
}

// ---------------- host launch ----------------

extern "C" void kernel_launch(void* const* d_in, const int* in_sizes, int n_in,
                              void* d_out, int out_size, void* d_ws, size_t ws_size,
                              hipStream_t stream) {
  const float* E          = (const float*)d_in[0];
  const float* R          = (const float*)d_in[1];
  const float* w_alle     = (const float*)d_in[2];
  const float* w_addpos   = (const float*)d_in[3];
  const float* w_alleandr = (const float*)d_in[4];
  const float* w_rel      = (const float*)d_in[5];
  const float* conv_w     = (const float*)d_in[6];
  const float* conv_b     = (const float*)d_in[7];
  const float* fc_w       = (const float*)d_in[8];
  const float* fc_b       = (const float*)d_in[9];
  const float* bnmp_g     = (const float*)d_in[10];
  const float* bnmp_b     = (const float*)d_in[11];
  const float* bn0_g      = (const float*)d_in[12];
  const float* bn0_b      = (const float*)d_in[13];
  const float* bn1_g      = (const float*)d_in[14];
  const float* bn1_b      = (const float*)d_in[15];
  const float* bn2_g      = (const float*)d_in[16];
  const float* bn2_b      = (const float*)d_in[17];
  const float* ms         = (const float*)d_in[18];
  const int* hyperedge    = (const int*)d_in[19];
  const int* edge_index   = (const int*)d_in[20];
  const int* edge_type    = (const int*)d_in[21];
  const int* r_idx        = (const int*)d_in[22];
  const int* e1 = (const int*)d_in[23];
  const int* e2 = (const int*)d_in[24];
  const int* e3 = (const int*)d_in[25];
  const int* e4 = (const int*)d_in[26];
  const int* e5 = (const int*)d_in[27];
  const int* e6 = (const int*)d_in[28];

  const int Nn    = in_sizes[0] / D;        // 50006
  const int NR    = in_sizes[1] / D;        // 2000
  const int Hh    = in_sizes[19] / 7;       // 100000
  const int NEdge = in_sizes[21];           // 600000
  const int B     = in_sizes[22];           // 2048
  const int ent   = Nn - 6;                 // == ent_num by construction
  const int K_fc  = in_sizes[8] / D;        // 39600
  const int KCH   = (K_fc + 127) / 128;     // 310
  const int KPAD  = KCH * 128;              // 39680
  const int KU32  = KPAD / 2;               // 19840
  const int chPerSeg = (KCH + FC_NSPLIT - 1) / FC_NSPLIT;  // 20
  const int KT_tot = KCH * 4;               // 1240
  const int NSLOT = 6 * B + 6;              // 12294
  const int MPAD  = ((Nn + 63) / 64) * 64;  // 50048
  const int NT_A = 38, NT_B = 50;

  const int* esrc = edge_index;
  const int* edst = edge_index + NEdge;

  char* W = (char*)d_ws;
  size_t off = 0;
  auto alloc = [&](size_t bytes) { size_t o = off; off += (bytes + 255) & ~(size_t)255; return o; };
  // persistent
  size_t o_Wfc  = alloc((size_t)KT_tot * 13 * 512 * 2);
  size_t o_WbpA = alloc((size_t)7 * NT_A * 512 * 2);
  size_t o_WbpB = alloc((size_t)7 * NT_B * 512 * 2);
  size_t o_Wtop = alloc((size_t)200 * 200 * 4);
  size_t o_T    = alloc((size_t)1200 * 200 * 4);
  size_t o_Rv   = alloc((size_t)NR * 200 * 4);
  size_t o_outR = alloc((size_t)NR * 200 * 4);
  size_t o_need = alloc(((size_t)Nn + 1) * 4);  // + cnt at [Nn]
  size_t o_list = alloc((size_t)NSLOT * 4 + 64);
  size_t o_deg  = alloc((size_t)NSLOT * 4 + 64);
  size_t o_rs   = alloc((size_t)NSLOT * 4 + 64);
  size_t o_epos = alloc((size_t)NEdge * 4);
  size_t o_elist= alloc((size_t)NEdge * 4);
  size_t o_outEc= alloc((size_t)NSLOT * 200 * 4);
  size_t o_stk  = alloc((size_t)B * 1400 * 4);
  // region A (phase-1: Pv|V|Ebf ; phase-2: x1|Ypart)
  size_t o_A    = off;
  size_t o_Pv   = alloc((size_t)MPAD * 800 * 2);
  size_t o_V    = alloc((size_t)Hh * 200 * 2);
  size_t o_Ebf  = alloc((size_t)MPAD * 200 * 2);
  size_t regionA_end = off;

  size_t x1_bytes = (size_t)BHALF * KPAD * 2;
  size_t o_x1 = o_A;
  size_t o_Yp = o_A + ((x1_bytes + 255) & ~(size_t)255);
  size_t yp_bytes = (size_t)FC_NSPLIT * BHALF * 208 * 4;
  if (ws_size < off) return;
  if (o_Yp + yp_bytes > regionA_end) return;

  unsigned short* Wfc  = (unsigned short*)(W + o_Wfc);
  unsigned short* WbpA = (unsigned short*)(W + o_WbpA);
  unsigned short* WbpB = (unsigned short*)(W + o_WbpB);
  float* Wtop  = (float*)(W + o_Wtop);
  float* T     = (float*)(W + o_T);
  float* Rv    = (float*)(W + o_Rv);
  float* outR  = (float*)(W + o_outR);
  int*   needed= (int*)(W + o_need);
  int*   cnt   = needed + Nn;
  int*   list  = (int*)(W + o_list);
  int*   deg   = (int*)(W + o_deg);
  int*   rs    = (int*)(W + o_rs);
  int*   epos  = (int*)(W + o_epos);
  int*   elist = (int*)(W + o_elist);
  float* outEc = (float*)(W + o_outEc);
  float* stk   = (float*)(W + o_stk);
  unsigned short* Pv  = (unsigned short*)(W + o_Pv);
  unsigned short* Vb  = (unsigned short*)(W + o_V);
  unsigned short* Ebf = (unsigned short*)(W + o_Ebf);
  unsigned short* x1  = (unsigned short*)(W + o_x1);
  float* Ypart        = (float*)(W + o_Yp);

  hipMemsetAsync(needed, 0, ((size_t)Nn + 1) * 4, stream);
  hipMemsetAsync(deg, 0, (size_t)NSLOT * 4, stream);

  // prep chain
  hipLaunchKernelGGL(k_cvt_bf16, dim3(4096), dim3(256), 0, stream, E, Ebf, Nn * D);
  hipLaunchKernelGGL(k_sgemm, dim3(25), dim3(256), 0, stream, w_alleandr, w_addpos, Wtop, 200, (const float*)nullptr, 1.0f);
  hipLaunchKernelGGL(k_sgemm, dim3(150), dim3(256), 0, stream, w_alle, Wtop, T, 1200, E + (size_t)ent * D, 0.5f);
  hipLaunchKernelGGL(k_sgemm, dim3(250), dim3(256), 0, stream, R, Wtop, Rv, NR, (const float*)nullptr, 0.5f);
  hipLaunchKernelGGL(k_sgemm, dim3(250), dim3(256), 0, stream, R, w_rel, outR, NR, (const float*)nullptr, 1.0f);
  hipLaunchKernelGGL(k_packB, dim3(7 * NT_A), dim3(64), 0, stream, T, w_addpos, WbpA, NT_A, 0, 0);
  hipLaunchKernelGGL(k_packB, dim3(7 * NT_B), dim3(64), 0, stream, T, w_addpos, WbpB, NT_B, 3, 1);
  hipLaunchKernelGGL(k_prep_wfc, dim3(KT_tot * 13), dim3(64), 0, stream, fc_w, Wfc, K_fc);

  // mask / compact / CSR
  hipLaunchKernelGGL(k_mask, dim3((6 * B + 6 + 255) / 256), dim3(256), 0, stream,
                     e1, e2, e3, e4, e5, e6, ent, needed, B);
  hipLaunchKernelGGL(k_compact, dim3((Nn + 255) / 256), dim3(256), 0, stream, needed, list, cnt, Nn);
  hipLaunchKernelGGL(k_ecount, dim3((NEdge + 255) / 256), dim3(256), 0, stream, esrc, needed, deg, epos, NEdge);
  hipLaunchKernelGGL(k_prefix, dim3(1), dim3(256), 0, stream, deg, rs, NSLOT);
  hipLaunchKernelGGL(k_efill, dim3((NEdge + 255) / 256), dim3(256), 0, stream, esrc, needed, rs, epos, elist, NEdge);

  // P / V pipeline (two N-passes sharing Pv buffer)
  hipLaunchKernelGGL(k_pgemm, dim3(MPAD / 64), dim3(256), 0, stream, (const u32*)Ebf, WbpA, Pv, NT_A);
  hipLaunchKernelGGL(k_vsum, dim3(Hh), dim3(128), 0, stream, (const u32*)Pv, Rv, hyperedge, (u32*)Vb, 0);
  hipLaunchKernelGGL(k_pgemm, dim3(MPAD / 64), dim3(256), 0, stream, (const u32*)Ebf, WbpB, Pv, NT_B);
  hipLaunchKernelGGL(k_vsum, dim3(Hh), dim3(128), 0, stream, (const u32*)Pv, Rv, hyperedge, (u32*)Vb, 3);

  // aggregate + outE (compact)
  hipLaunchKernelGGL(k_gagg, dim3(NSLOT), dim3(128), 0, stream,
                     list, cnt, deg, rs, elist, edge_type, edst,
                     (const u32*)Vb, (const u32*)Pv, E, bnmp_g, bnmp_b, outEc);

  // stk
  hipLaunchKernelGGL(k_stk, dim3(B), dim3(256), 0, stream,
                     outEc, outR, needed, r_idx, e1, e2, e3, e4, e5, e6, ms, ent, bn0_g, bn0_b, stk);

  // conv + fc + epilogue in two half-batches (x1/Ypart alias phase-1 buffers)
  for (int half = 0; half < 2; ++half) {
    int b0 = half * BHALF;
    hipLaunchKernelGGL(k_conv, dim3(BHALF), dim3(256), 0, stream, stk, conv_w, conv_b, bn1_g, bn1_b, x1, KPAD, b0);
    hipLaunchKernelGGL(k_fcgemm, dim3((BHALF / 32) * FC_NSPLIT), dim3(256), 0, stream,
                       (const u32*)x1, Wfc, Ypart, BHALF, KU32, KCH, chPerSeg);
    hipLaunchKernelGGL(k_epilogue, dim3(BHALF), dim3(256), 0, stream, Ypart, fc_b, bn2_g, bn2_b, (float*)d_out, BHALF, b0);
  }
}